// Round 4
// baseline (555.020 us; speedup 1.0000x reference)
//
#include <hip/hip_runtime.h>
#include <hip/hip_bf16.h>
#include <math.h>

#define HW 6400
#define NC 512
#define NH 80
#define NW 80
#define NCH 25      // column chunks (blocks in y)
#define NSLOT 50    // per-row partial slots = NCH * 2 (two col-waves per block)
#define JCH 256     // columns per block
#define TI 128      // row tile per block
#define BK 64       // K tile

typedef __attribute__((ext_vector_type(8))) short short8;
typedef __attribute__((ext_vector_type(4))) float v4f;

// ---- workspace layout (float offsets) ----
#define MU_OFF    0
#define INVD_OFF  512
#define GMAXP_OFF (512 + HW)               // HW*NSLOT; also aliased by psx/psy (dead after transpose)
#define ZP_OFF    (GMAXP_OFF + HW*NSLOT)   // HW*NSLOT
#define ACC_OFF   (ZP_OFF + HW*NSLOT)
#define F32_FLOATS (ACC_OFF + 64)
#define XB_BYTE   ((size_t)(((F32_FLOATS*4) + 255) & ~255))
#define YB_BYTE   (XB_BYTE + (size_t)HW*NC*2)

__global__ void k_mu(const float* __restrict__ y, float* __restrict__ mu) {
    int c = blockIdx.x;
    const float* yc = y + (size_t)c * HW;
    float s = 0.f;
    for (int i = threadIdx.x; i < HW; i += 256) s += yc[i];
    __shared__ float red[256];
    red[threadIdx.x] = s;
    __syncthreads();
    for (int off = 128; off > 0; off >>= 1) {
        if (threadIdx.x < off) red[threadIdx.x] += red[threadIdx.x + off];
        __syncthreads();
    }
    if (threadIdx.x == 0) mu[c] = red[0] * (1.0f / HW);
}

// partial sum-of-squares over a 64-channel chunk; grid (HW/256, NC/64)
__global__ void k_sumsq(const float* __restrict__ x, const float* __restrict__ y,
                        const float* __restrict__ mu,
                        float* __restrict__ psx, float* __restrict__ psy) {
    int i = blockIdx.x * 256 + threadIdx.x;
    int c0 = blockIdx.y * 64;
    float sx = 0.f, sy = 0.f;
    for (int c = c0; c < c0 + 64; ++c) {
        float m = mu[c];
        float dx = x[(size_t)c * HW + i] - m;
        float dy = y[(size_t)c * HW + i] - m;
        sx = fmaf(dx, dx, sx);
        sy = fmaf(dy, dy, sy);
    }
    psx[(size_t)blockIdx.y * HW + i] = sx;
    psy[(size_t)blockIdx.y * HW + i] = sy;
}

// normalized bf16 transpose: src [c][i] fp32 -> dst [i][c] bf16; z picks x or y
__global__ void k_transpose(const float* __restrict__ x, const float* __restrict__ y,
                            const float* __restrict__ mu,
                            const float* __restrict__ psx, const float* __restrict__ psy,
                            unsigned short* __restrict__ xb, unsigned short* __restrict__ yb) {
    __shared__ float tile[64 * 68];
    __shared__ float ssinv[64];
    const int t = threadIdx.x;
    const int i0 = blockIdx.x * 64;
    const int c0 = blockIdx.y * 64;
    const int z = blockIdx.z;
    const float* src = z ? y : x;
    const float* ps  = z ? psy : psx;
    unsigned short* dst = z ? yb : xb;

    if (t < 64) {
        float s = 0.f;
        #pragma unroll
        for (int p = 0; p < 8; ++p) s += ps[(size_t)p * HW + i0 + t];
        ssinv[t] = 1.0f / fmaxf(sqrtf(s), 1e-12f);
    }
    __syncthreads();
    #pragma unroll 4
    for (int it = 0; it < 16; ++it) {
        int cl = it * 4 + (t >> 6);
        int il = t & 63;
        float v = (src[(size_t)(c0 + cl) * HW + i0 + il] - mu[c0 + cl]) * ssinv[il];
        tile[il * 68 + cl] = v;
    }
    __syncthreads();
    #pragma unroll
    for (int it = 0; it < 2; ++it) {
        int il = t >> 2;
        int seg = (t & 3) + it * 4;
        unsigned int pk[4];
        #pragma unroll
        for (int p = 0; p < 4; ++p) {
            float v0 = tile[il * 68 + seg * 8 + p * 2];
            float v1 = tile[il * 68 + seg * 8 + p * 2 + 1];
            __hip_bfloat16 h0 = __float2bfloat16(v0);
            __hip_bfloat16 h1 = __float2bfloat16(v1);
            unsigned short u0 = *reinterpret_cast<unsigned short*>(&h0);
            unsigned short u1 = *reinterpret_cast<unsigned short*>(&h1);
            pk[p] = (unsigned int)u0 | ((unsigned int)u1 << 16);
        }
        uint4 val = make_uint4(pk[0], pk[1], pk[2], pk[3]);
        *(uint4*)&dst[(size_t)(i0 + il) * NC + c0 + seg * 8] = val;
    }
}

// MFMA GEMM driver. Block: rows [i0,i0+128) x cols [jbase,jbase+256) in two
// 128x128 jt-tiles. 4 waves in 2x2: wave computes 64x64 (4x4 16x16 tiles).
// Register prefetch: next kt's global loads issue after the staging barrier.
template <typename F>
__device__ __forceinline__ void gemm_driver(const unsigned short* __restrict__ Xb,
                                            const unsigned short* __restrict__ Yb,
                                            F&& consume) {
    __shared__ char sA[TI * BK * 2];   // [row][k], 128 B/row, seg^(row&7) swizzle
    __shared__ char sB[TI * BK * 2];
    const int t = threadIdx.x;
    const int w = t >> 6, l = t & 63;
    const int wr = w >> 1, wc = w & 1;
    const int lr = l & 15, lg = l >> 4;
    const int i0 = blockIdx.x * TI;
    const int jbase = blockIdx.y * JCH;

    int aoff[4][2], boff[4][2];
    #pragma unroll
    for (int mt = 0; mt < 4; ++mt) {
        int row = wr * 64 + mt * 16 + lr;
        #pragma unroll
        for (int ks = 0; ks < 2; ++ks) {
            int seg = ks * 4 + lg;
            aoff[mt][ks] = row * 128 + ((seg ^ (row & 7)) * 16);
        }
    }
    #pragma unroll
    for (int nt = 0; nt < 4; ++nt) {
        int row = wc * 64 + nt * 16 + lr;
        #pragma unroll
        for (int ks = 0; ks < 2; ++ks) {
            int seg = ks * 4 + lg;
            boff[nt][ks] = row * 128 + ((seg ^ (row & 7)) * 16);
        }
    }
    int srow[4], swoff[4];
    #pragma unroll
    for (int it = 0; it < 4; ++it) {
        int c = t + it * 256;
        srow[it] = c >> 3;
        swoff[it] = srow[it] * 128 + (((c & 7) ^ (srow[it] & 7)) * 16);
    }
    const int sseg8 = (t & 7) * 8;

    uint4 av[4], bv[4];
    auto load_tiles = [&](int jt, int kt) {
        #pragma unroll
        for (int it = 0; it < 4; ++it) {
            av[it] = *(const uint4*)(Xb + (size_t)(i0 + srow[it]) * NC + kt + sseg8);
            bv[it] = *(const uint4*)(Yb + (size_t)(jbase + jt + srow[it]) * NC + kt + sseg8);
        }
    };

    load_tiles(0, 0);

    #pragma unroll 1
    for (int jt = 0; jt < JCH; jt += TI) {
        v4f acc[4][4];
        #pragma unroll
        for (int mt = 0; mt < 4; ++mt)
            #pragma unroll
            for (int nt = 0; nt < 4; ++nt)
                acc[mt][nt] = (v4f){0.f, 0.f, 0.f, 0.f};

        #pragma unroll 1
        for (int kt = 0; kt < NC; kt += BK) {
            __syncthreads();
            #pragma unroll
            for (int it = 0; it < 4; ++it) {
                *(uint4*)&sA[swoff[it]] = av[it];
                *(uint4*)&sB[swoff[it]] = bv[it];
            }
            __syncthreads();
            {
                int nkt = kt + BK, njt = jt;
                if (nkt == NC) { nkt = 0; njt = jt + TI; }
                if (njt < JCH) load_tiles(njt, nkt);
            }
            #pragma unroll
            for (int ks = 0; ks < 2; ++ks) {
                short8 af[4], bf[4];
                #pragma unroll
                for (int mt = 0; mt < 4; ++mt) af[mt] = *(const short8*)&sA[aoff[mt][ks]];
                #pragma unroll
                for (int nt = 0; nt < 4; ++nt) bf[nt] = *(const short8*)&sB[boff[nt][ks]];
                #pragma unroll
                for (int mt = 0; mt < 4; ++mt)
                    #pragma unroll
                    for (int nt = 0; nt < 4; ++nt)
                        acc[mt][nt] = __builtin_amdgcn_mfma_f32_16x16x32_bf16(
                            af[mt], bf[nt], acc[mt][nt], 0, 0, 0);
            }
        }
        consume(acc, jt);
    }
}

__global__ __launch_bounds__(256, 2) void k_pass1(const unsigned short* __restrict__ Xb,
                                                  const unsigned short* __restrict__ Yb,
                                                  float* __restrict__ gmaxp) {
    const int t = threadIdx.x;
    const int w = t >> 6, l = t & 63;
    const int wr = w >> 1, wc = w & 1;
    const int lr = l & 15, lg = l >> 4;
    const int i0 = blockIdx.x * TI;
    float rmax[16];
    #pragma unroll
    for (int u = 0; u < 16; ++u) rmax[u] = -3.0e38f;

    gemm_driver(Xb, Yb, [&](v4f (&acc)[4][4], int jt) {
        (void)jt;
        #pragma unroll
        for (int mt = 0; mt < 4; ++mt)
            #pragma unroll
            for (int r = 0; r < 4; ++r) {
                float m = acc[mt][0][r];
                #pragma unroll
                for (int nt = 1; nt < 4; ++nt) m = fmaxf(m, acc[mt][nt][r]);
                rmax[mt * 4 + r] = fmaxf(rmax[mt * 4 + r], m);
            }
    });

    #pragma unroll
    for (int u = 0; u < 16; ++u) {
        float v = rmax[u];
        v = fmaxf(v, __shfl_xor(v, 1));
        v = fmaxf(v, __shfl_xor(v, 2));
        v = fmaxf(v, __shfl_xor(v, 4));
        v = fmaxf(v, __shfl_xor(v, 8));
        if (lr == 0) {
            int row = i0 + wr * 64 + (u >> 2) * 16 + lg * 4 + (u & 3);
            gmaxp[(size_t)row * NSLOT + blockIdx.y * 2 + wc] = v;
        }
    }
}

__global__ void k_invd(const float* __restrict__ gmaxp, float* __restrict__ invd) {
    int i = blockIdx.x * 256 + threadIdx.x;
    float m = -3.0e38f;
    #pragma unroll
    for (int s = 0; s < NSLOT; ++s) m = fmaxf(m, gmaxp[(size_t)i * NSLOT + s]);
    invd[i] = 1.0f / ((1.0f - m) + 1e-5f);
}

__global__ __launch_bounds__(256, 2) void k_pass2(const unsigned short* __restrict__ Xb,
                                                  const unsigned short* __restrict__ Yb,
                                                  const float* __restrict__ invd,
                                                  float* __restrict__ zp) {
    const int t = threadIdx.x;
    const int w = t >> 6, l = t & 63;
    const int wr = w >> 1, wc = w & 1;
    const int lr = l & 15, lg = l >> 4;
    const int i0 = blockIdx.x * TI;

    float zs[16], c1[16], c2[16];
    #pragma unroll
    for (int u = 0; u < 16; ++u) {
        int row = i0 + wr * 64 + (u >> 2) * 16 + lg * 4 + (u & 3);
        float inv = invd[row];
        c2[u] = 2.0f * inv;          // w = exp(c1 + c2*g)
        c1[u] = 2.0f - 2.0f * inv;
        zs[u] = 0.f;
    }

    gemm_driver(Xb, Yb, [&](v4f (&acc)[4][4], int jt) {
        (void)jt;
        #pragma unroll
        for (int mt = 0; mt < 4; ++mt)
            #pragma unroll
            for (int r = 0; r < 4; ++r) {
                int u = mt * 4 + r;
                float s = 0.f;
                #pragma unroll
                for (int nt = 0; nt < 4; ++nt)
                    s += __expf(fmaf(c2[u], acc[mt][nt][r], c1[u]));
                zs[u] += s;
            }
    });

    #pragma unroll
    for (int u = 0; u < 16; ++u) {
        float z = zs[u];
        z += __shfl_xor(z, 1);
        z += __shfl_xor(z, 2);
        z += __shfl_xor(z, 4);
        z += __shfl_xor(z, 8);
        if (lr == 0) {
            int row = i0 + wr * 64 + (u >> 2) * 16 + lg * 4 + (u & 3);
            zp[(size_t)row * NSLOT + blockIdx.y * 2 + wc] = z;
        }
    }
}

__global__ void k_kmax(const float* __restrict__ zp, const float* __restrict__ gmaxp,
                       const unsigned short* __restrict__ Xb, const unsigned short* __restrict__ Yb,
                       float* __restrict__ accum) {
    int i = blockIdx.x * 256 + threadIdx.x;
    float Z = 0.f, gmax = -3.0e38f;
    #pragma unroll
    for (int s = 0; s < NSLOT; ++s) {
        Z += zp[(size_t)i * NSLOT + s];
        gmax = fmaxf(gmax, gmaxp[(size_t)i * NSLOT + s]);
    }
    // diagonal cos: dot of normalized bf16 rows
    float gii = 0.f;
    const uint2* xr = (const uint2*)(Xb + (size_t)i * NC);
    const uint2* yr = (const uint2*)(Yb + (size_t)i * NC);
    for (int c4 = 0; c4 < NC / 4; ++c4) {
        uint2 xa = xr[c4], ya = yr[c4];
        float x0 = __uint_as_float((xa.x & 0xFFFFu) << 16), y0 = __uint_as_float((ya.x & 0xFFFFu) << 16);
        float x1 = __uint_as_float(xa.x & 0xFFFF0000u),     y1 = __uint_as_float(ya.x & 0xFFFF0000u);
        float x2 = __uint_as_float((xa.y & 0xFFFFu) << 16), y2 = __uint_as_float((ya.y & 0xFFFFu) << 16);
        float x3 = __uint_as_float(xa.y & 0xFFFF0000u),     y3 = __uint_as_float(ya.y & 0xFFFF0000u);
        gii = fmaf(x0, y0, gii); gii = fmaf(x1, y1, gii);
        gii = fmaf(x2, y2, gii); gii = fmaf(x3, y3, gii);
    }
    float dmin = 1.0f - gmax;
    float inv = 1.0f / (dmin + 1e-5f);
    float wmx = __expf(2.0f - 2.0f * dmin * inv);                  // w at g = gmax
    float wii = __expf(2.0f - 2.0f * (1.0f - gii) * inv);          // w at diagonal
    float invZ = 1.0f / Z;
    // spatial branch: cx_sp == identity in fp32 (off-diag ~5.8e-14 underflows row sum)
    float kmax = fmaxf(0.9f * wmx * invZ, 0.9f * wii * invZ + 0.1f);

    __shared__ float red[256];
    red[threadIdx.x] = kmax;
    __syncthreads();
    for (int off = 128; off > 0; off >>= 1) {
        if (threadIdx.x < off) red[threadIdx.x] += red[threadIdx.x + off];
        __syncthreads();
    }
    if (threadIdx.x == 0) atomicAdd(accum, red[0]);
}

__global__ void k_final(const float* __restrict__ accum, float* __restrict__ out) {
    out[0] = -logf(accum[0] * (1.0f / HW) + 1e-5f);
}

extern "C" void kernel_launch(void* const* d_in, const int* in_sizes, int n_in,
                              void* d_out, int out_size, void* d_ws, size_t ws_size,
                              hipStream_t stream) {
    const float* x = (const float*)d_in[0];
    const float* y = (const float*)d_in[1];
    float* out = (float*)d_out;
    float* ws = (float*)d_ws;

    float* mu    = ws + MU_OFF;
    float* invd  = ws + INVD_OFF;
    float* gmaxp = ws + GMAXP_OFF;
    float* psx   = ws + GMAXP_OFF;            // aliases gmaxp (dead before pass1)
    float* psy   = ws + GMAXP_OFF + 8 * HW;
    float* zp    = ws + ZP_OFF;
    float* accum = ws + ACC_OFF;
    unsigned short* Xb = (unsigned short*)((char*)d_ws + XB_BYTE);
    unsigned short* Yb = (unsigned short*)((char*)d_ws + YB_BYTE);

    hipMemsetAsync(accum, 0, sizeof(float), stream);

    hipLaunchKernelGGL(k_mu, dim3(NC), dim3(256), 0, stream, y, mu);
    hipLaunchKernelGGL(k_sumsq, dim3(HW / 256, NC / 64), dim3(256), 0, stream, x, y, mu, psx, psy);
    hipLaunchKernelGGL(k_transpose, dim3(HW / 64, NC / 64, 2), dim3(256), 0, stream,
                       x, y, mu, psx, psy, Xb, Yb);

    dim3 grid(HW / TI, NCH);
    hipLaunchKernelGGL(k_pass1, grid, dim3(256), 0, stream, Xb, Yb, gmaxp);
    hipLaunchKernelGGL(k_invd, dim3(HW / 256), dim3(256), 0, stream, gmaxp, invd);
    hipLaunchKernelGGL(k_pass2, grid, dim3(256), 0, stream, Xb, Yb, invd, zp);
    hipLaunchKernelGGL(k_kmax, dim3(HW / 256), dim3(256), 0, stream, zp, gmaxp, Xb, Yb, accum);
    hipLaunchKernelGGL(k_final, dim3(1), dim3(1), 0, stream, accum, out);
}

// Round 5
// 224.325 us; speedup vs baseline: 2.4742x; 2.4742x over previous
//
#include <hip/hip_runtime.h>
#include <hip/hip_bf16.h>
#include <math.h>

#define HW 6400
#define NC 512
#define NH 80
#define NW 80
#define NCH 25      // column chunks (blocks in y)
#define NSLOT 50    // per-row partial slots = NCH * 2 (two col-waves per block)
#define JCH 256     // columns per block
#define TI 128      // row tile per block
#define BK 64       // K tile

typedef __attribute__((ext_vector_type(8))) short short8;
typedef __attribute__((ext_vector_type(4))) float v4f;

// ---- workspace layout (float offsets) ----
#define MU_OFF    0
#define INVD_OFF  512
#define GMAXP_OFF (512 + HW)               // HW*NSLOT; aliased by psx/psy pre-pass1
#define ZP_OFF    (GMAXP_OFF + HW*NSLOT)   // HW*NSLOT
#define ACC_OFF   (ZP_OFF + HW*NSLOT)
#define F32_FLOATS (ACC_OFF + 64)
#define XB_BYTE   ((size_t)(((F32_FLOATS*4) + 255) & ~255))
#define YB_BYTE   (XB_BYTE + (size_t)HW*NC*2)

__global__ void k_mu(const float* __restrict__ y, float* __restrict__ mu) {
    int c = blockIdx.x;
    const float* yc = y + (size_t)c * HW;
    float s = 0.f;
    for (int i = threadIdx.x; i < HW; i += 256) s += yc[i];
    __shared__ float red[256];
    red[threadIdx.x] = s;
    __syncthreads();
    for (int off = 128; off > 0; off >>= 1) {
        if (threadIdx.x < off) red[threadIdx.x] += red[threadIdx.x + off];
        __syncthreads();
    }
    if (threadIdx.x == 0) mu[c] = red[0] * (1.0f / HW);
}

// partial sum-of-squares over a 64-channel chunk; grid (HW/256, NC/64)
__global__ void k_sumsq(const float* __restrict__ x, const float* __restrict__ y,
                        const float* __restrict__ mu,
                        float* __restrict__ psx, float* __restrict__ psy) {
    int i = blockIdx.x * 256 + threadIdx.x;
    int c0 = blockIdx.y * 64;
    float sx = 0.f, sy = 0.f;
    for (int c = c0; c < c0 + 64; ++c) {
        float m = mu[c];
        float dx = x[(size_t)c * HW + i] - m;
        float dy = y[(size_t)c * HW + i] - m;
        sx = fmaf(dx, dx, sx);
        sy = fmaf(dy, dy, sy);
    }
    psx[(size_t)blockIdx.y * HW + i] = sx;
    psy[(size_t)blockIdx.y * HW + i] = sy;
}

// normalized bf16 transpose: src [c][i] fp32 -> dst [i][c] bf16; z picks x or y
__global__ void k_transpose(const float* __restrict__ x, const float* __restrict__ y,
                            const float* __restrict__ mu,
                            const float* __restrict__ psx, const float* __restrict__ psy,
                            unsigned short* __restrict__ xb, unsigned short* __restrict__ yb) {
    __shared__ float tile[64 * 68];
    __shared__ float ssinv[64];
    const int t = threadIdx.x;
    const int i0 = blockIdx.x * 64;
    const int c0 = blockIdx.y * 64;
    const int z = blockIdx.z;
    const float* src = z ? y : x;
    const float* ps  = z ? psy : psx;
    unsigned short* dst = z ? yb : xb;

    if (t < 64) {
        float s = 0.f;
        #pragma unroll
        for (int p = 0; p < 8; ++p) s += ps[(size_t)p * HW + i0 + t];
        ssinv[t] = 1.0f / fmaxf(sqrtf(s), 1e-12f);
    }
    __syncthreads();
    #pragma unroll 4
    for (int it = 0; it < 16; ++it) {
        int cl = it * 4 + (t >> 6);
        int il = t & 63;
        float v = (src[(size_t)(c0 + cl) * HW + i0 + il] - mu[c0 + cl]) * ssinv[il];
        tile[il * 68 + cl] = v;
    }
    __syncthreads();
    #pragma unroll
    for (int it = 0; it < 2; ++it) {
        int il = t >> 2;
        int seg = (t & 3) + it * 4;
        unsigned int pk[4];
        #pragma unroll
        for (int p = 0; p < 4; ++p) {
            float v0 = tile[il * 68 + seg * 8 + p * 2];
            float v1 = tile[il * 68 + seg * 8 + p * 2 + 1];
            __hip_bfloat16 h0 = __float2bfloat16(v0);
            __hip_bfloat16 h1 = __float2bfloat16(v1);
            unsigned short u0 = *reinterpret_cast<unsigned short*>(&h0);
            unsigned short u1 = *reinterpret_cast<unsigned short*>(&h1);
            pk[p] = (unsigned int)u0 | ((unsigned int)u1 << 16);
        }
        uint4 val = make_uint4(pk[0], pk[1], pk[2], pk[3]);
        *(uint4*)&dst[(size_t)(i0 + il) * NC + c0 + seg * 8] = val;
    }
}

// MFMA GEMM driver. Block: rows [i0,i0+128) x cols [jbase,jbase+256) in two
// 128x128 jt-tiles. 4 waves in 2x2: wave computes 64x64 (4x4 16x16 tiles).
// Register prefetch in NAMED SCALARS (no lambda/array: R3/R4's lambda-captured
// uint4 arrays failed SROA and spilled 600 MB to scratch).
template <typename F>
__device__ __forceinline__ void gemm_driver(const unsigned short* __restrict__ Xb,
                                            const unsigned short* __restrict__ Yb,
                                            F&& consume) {
    __shared__ char sA[TI * BK * 2];   // [row][k], 128 B/row, seg^(row&7) swizzle
    __shared__ char sB[TI * BK * 2];
    const int t = threadIdx.x;
    const int w = t >> 6, l = t & 63;
    const int wr = w >> 1, wc = w & 1;
    const int lr = l & 15, lg = l >> 4;
    const int i0 = blockIdx.x * TI;
    const int jbase = blockIdx.y * JCH;

    int aoff[4][2], boff[4][2];
    #pragma unroll
    for (int mt = 0; mt < 4; ++mt) {
        int row = wr * 64 + mt * 16 + lr;
        #pragma unroll
        for (int ks = 0; ks < 2; ++ks) {
            int seg = ks * 4 + lg;
            aoff[mt][ks] = row * 128 + ((seg ^ (row & 7)) * 16);
        }
    }
    #pragma unroll
    for (int nt = 0; nt < 4; ++nt) {
        int row = wc * 64 + nt * 16 + lr;
        #pragma unroll
        for (int ks = 0; ks < 2; ++ks) {
            int seg = ks * 4 + lg;
            boff[nt][ks] = row * 128 + ((seg ^ (row & 7)) * 16);
        }
    }
    // staging chunk geometry, scalarized (chunk = row*8+seg, this thread: t+256*it)
    const int sr0 = t >> 3,           sr1 = (t + 256) >> 3;
    const int sr2 = (t + 512) >> 3,   sr3 = (t + 768) >> 3;
    const int sg  = t & 7;
    const int sw0 = sr0 * 128 + ((sg ^ (sr0 & 7)) * 16);
    const int sw1 = sr1 * 128 + ((sg ^ (sr1 & 7)) * 16);
    const int sw2 = sr2 * 128 + ((sg ^ (sr2 & 7)) * 16);
    const int sw3 = sr3 * 128 + ((sg ^ (sr3 & 7)) * 16);
    const int sseg8 = sg * 8;

    // loop-invariant row base pointers
    const unsigned short* pa0 = Xb + (size_t)(i0 + sr0) * NC + sseg8;
    const unsigned short* pa1 = Xb + (size_t)(i0 + sr1) * NC + sseg8;
    const unsigned short* pa2 = Xb + (size_t)(i0 + sr2) * NC + sseg8;
    const unsigned short* pa3 = Xb + (size_t)(i0 + sr3) * NC + sseg8;
    const unsigned short* pb0 = Yb + (size_t)(jbase + sr0) * NC + sseg8;
    const unsigned short* pb1 = Yb + (size_t)(jbase + sr1) * NC + sseg8;
    const unsigned short* pb2 = Yb + (size_t)(jbase + sr2) * NC + sseg8;
    const unsigned short* pb3 = Yb + (size_t)(jbase + sr3) * NC + sseg8;

    uint4 av0, av1, av2, av3, bv0, bv1, bv2, bv3;
    // initial prefetch (jt=0, kt=0)
    av0 = *(const uint4*)(pa0); av1 = *(const uint4*)(pa1);
    av2 = *(const uint4*)(pa2); av3 = *(const uint4*)(pa3);
    bv0 = *(const uint4*)(pb0); bv1 = *(const uint4*)(pb1);
    bv2 = *(const uint4*)(pb2); bv3 = *(const uint4*)(pb3);

    #pragma unroll 1
    for (int jt = 0; jt < JCH; jt += TI) {
        v4f acc[4][4];
        #pragma unroll
        for (int mt = 0; mt < 4; ++mt)
            #pragma unroll
            for (int nt = 0; nt < 4; ++nt)
                acc[mt][nt] = (v4f){0.f, 0.f, 0.f, 0.f};

        #pragma unroll 1
        for (int kt = 0; kt < NC; kt += BK) {
            __syncthreads();
            *(uint4*)&sA[sw0] = av0; *(uint4*)&sA[sw1] = av1;
            *(uint4*)&sA[sw2] = av2; *(uint4*)&sA[sw3] = av3;
            *(uint4*)&sB[sw0] = bv0; *(uint4*)&sB[sw1] = bv1;
            *(uint4*)&sB[sw2] = bv2; *(uint4*)&sB[sw3] = bv3;
            __syncthreads();
            // prefetch next stage (clamped to (0,0) on the final iteration;
            // uniform predicate, harmless redundant load)
            {
                int nkt = kt + BK, njt = jt;
                if (nkt == NC) { nkt = 0; njt += TI; }
                if (njt >= JCH) { nkt = 0; njt = 0; }
                int ao = nkt;               // element offset into A rows
                int bo = njt * NC + nkt;    // element offset into B rows
                av0 = *(const uint4*)(pa0 + ao); av1 = *(const uint4*)(pa1 + ao);
                av2 = *(const uint4*)(pa2 + ao); av3 = *(const uint4*)(pa3 + ao);
                bv0 = *(const uint4*)(pb0 + bo); bv1 = *(const uint4*)(pb1 + bo);
                bv2 = *(const uint4*)(pb2 + bo); bv3 = *(const uint4*)(pb3 + bo);
            }
            #pragma unroll
            for (int ks = 0; ks < 2; ++ks) {
                short8 af[4], bf[4];
                #pragma unroll
                for (int mt = 0; mt < 4; ++mt) af[mt] = *(const short8*)&sA[aoff[mt][ks]];
                #pragma unroll
                for (int nt = 0; nt < 4; ++nt) bf[nt] = *(const short8*)&sB[boff[nt][ks]];
                #pragma unroll
                for (int mt = 0; mt < 4; ++mt)
                    #pragma unroll
                    for (int nt = 0; nt < 4; ++nt)
                        acc[mt][nt] = __builtin_amdgcn_mfma_f32_16x16x32_bf16(
                            af[mt], bf[nt], acc[mt][nt], 0, 0, 0);
            }
        }
        consume(acc, jt);
    }
}

__global__ __launch_bounds__(256, 2) void k_pass1(const unsigned short* __restrict__ Xb,
                                                  const unsigned short* __restrict__ Yb,
                                                  float* __restrict__ gmaxp) {
    const int t = threadIdx.x;
    const int w = t >> 6, l = t & 63;
    const int wr = w >> 1, wc = w & 1;
    const int lr = l & 15, lg = l >> 4;
    const int i0 = blockIdx.x * TI;
    float rmax[16];
    #pragma unroll
    for (int u = 0; u < 16; ++u) rmax[u] = -3.0e38f;

    gemm_driver(Xb, Yb, [&](v4f (&acc)[4][4], int jt) {
        (void)jt;
        #pragma unroll
        for (int mt = 0; mt < 4; ++mt)
            #pragma unroll
            for (int r = 0; r < 4; ++r) {
                float m = acc[mt][0][r];
                #pragma unroll
                for (int nt = 1; nt < 4; ++nt) m = fmaxf(m, acc[mt][nt][r]);
                rmax[mt * 4 + r] = fmaxf(rmax[mt * 4 + r], m);
            }
    });

    #pragma unroll
    for (int u = 0; u < 16; ++u) {
        float v = rmax[u];
        v = fmaxf(v, __shfl_xor(v, 1));
        v = fmaxf(v, __shfl_xor(v, 2));
        v = fmaxf(v, __shfl_xor(v, 4));
        v = fmaxf(v, __shfl_xor(v, 8));
        if (lr == 0) {
            int row = i0 + wr * 64 + (u >> 2) * 16 + lg * 4 + (u & 3);
            gmaxp[(size_t)row * NSLOT + blockIdx.y * 2 + wc] = v;
        }
    }
}

__global__ void k_invd(const float* __restrict__ gmaxp, float* __restrict__ invd) {
    int i = blockIdx.x * 256 + threadIdx.x;
    float m = -3.0e38f;
    #pragma unroll
    for (int s = 0; s < NSLOT; ++s) m = fmaxf(m, gmaxp[(size_t)i * NSLOT + s]);
    invd[i] = 1.0f / ((1.0f - m) + 1e-5f);
}

__global__ __launch_bounds__(256, 2) void k_pass2(const unsigned short* __restrict__ Xb,
                                                  const unsigned short* __restrict__ Yb,
                                                  const float* __restrict__ invd,
                                                  float* __restrict__ zp) {
    const int t = threadIdx.x;
    const int w = t >> 6, l = t & 63;
    const int wr = w >> 1, wc = w & 1;
    const int lr = l & 15, lg = l >> 4;
    const int i0 = blockIdx.x * TI;

    float zs[16], c1[16], c2[16];
    #pragma unroll
    for (int u = 0; u < 16; ++u) {
        int row = i0 + wr * 64 + (u >> 2) * 16 + lg * 4 + (u & 3);
        float inv = invd[row];
        c2[u] = 2.0f * inv;          // w = exp(c1 + c2*g)
        c1[u] = 2.0f - 2.0f * inv;
        zs[u] = 0.f;
    }

    gemm_driver(Xb, Yb, [&](v4f (&acc)[4][4], int jt) {
        (void)jt;
        #pragma unroll
        for (int mt = 0; mt < 4; ++mt)
            #pragma unroll
            for (int r = 0; r < 4; ++r) {
                int u = mt * 4 + r;
                float s = 0.f;
                #pragma unroll
                for (int nt = 0; nt < 4; ++nt)
                    s += __expf(fmaf(c2[u], acc[mt][nt][r], c1[u]));
                zs[u] += s;
            }
    });

    #pragma unroll
    for (int u = 0; u < 16; ++u) {
        float z = zs[u];
        z += __shfl_xor(z, 1);
        z += __shfl_xor(z, 2);
        z += __shfl_xor(z, 4);
        z += __shfl_xor(z, 8);
        if (lr == 0) {
            int row = i0 + wr * 64 + (u >> 2) * 16 + lg * 4 + (u & 3);
            zp[(size_t)row * NSLOT + blockIdx.y * 2 + wc] = z;
        }
    }
}

__global__ void k_kmax(const float* __restrict__ zp, const float* __restrict__ gmaxp,
                       const unsigned short* __restrict__ Xb, const unsigned short* __restrict__ Yb,
                       float* __restrict__ accum) {
    int i = blockIdx.x * 256 + threadIdx.x;
    float Z = 0.f, gmax = -3.0e38f;
    #pragma unroll
    for (int s = 0; s < NSLOT; ++s) {
        Z += zp[(size_t)i * NSLOT + s];
        gmax = fmaxf(gmax, gmaxp[(size_t)i * NSLOT + s]);
    }
    // diagonal cos: dot of normalized bf16 rows
    float gii = 0.f;
    const uint2* xr = (const uint2*)(Xb + (size_t)i * NC);
    const uint2* yr = (const uint2*)(Yb + (size_t)i * NC);
    for (int c4 = 0; c4 < NC / 4; ++c4) {
        uint2 xa = xr[c4], ya = yr[c4];
        float x0 = __uint_as_float((xa.x & 0xFFFFu) << 16), y0 = __uint_as_float((ya.x & 0xFFFFu) << 16);
        float x1 = __uint_as_float(xa.x & 0xFFFF0000u),     y1 = __uint_as_float(ya.x & 0xFFFF0000u);
        float x2 = __uint_as_float((xa.y & 0xFFFFu) << 16), y2 = __uint_as_float((ya.y & 0xFFFFu) << 16);
        float x3 = __uint_as_float(xa.y & 0xFFFF0000u),     y3 = __uint_as_float(ya.y & 0xFFFF0000u);
        gii = fmaf(x0, y0, gii); gii = fmaf(x1, y1, gii);
        gii = fmaf(x2, y2, gii); gii = fmaf(x3, y3, gii);
    }
    float dmin = 1.0f - gmax;
    float inv = 1.0f / (dmin + 1e-5f);
    float wmx = __expf(2.0f - 2.0f * dmin * inv);                  // w at g = gmax
    float wii = __expf(2.0f - 2.0f * (1.0f - gii) * inv);          // w at diagonal
    float invZ = 1.0f / Z;
    // spatial branch: cx_sp == identity in fp32 (off-diag ~5.8e-14 underflows row sum)
    float kmax = fmaxf(0.9f * wmx * invZ, 0.9f * wii * invZ + 0.1f);

    __shared__ float red[256];
    red[threadIdx.x] = kmax;
    __syncthreads();
    for (int off = 128; off > 0; off >>= 1) {
        if (threadIdx.x < off) red[threadIdx.x] += red[threadIdx.x + off];
        __syncthreads();
    }
    if (threadIdx.x == 0) atomicAdd(accum, red[0]);
}

__global__ void k_final(const float* __restrict__ accum, float* __restrict__ out) {
    out[0] = -logf(accum[0] * (1.0f / HW) + 1e-5f);
}

extern "C" void kernel_launch(void* const* d_in, const int* in_sizes, int n_in,
                              void* d_out, int out_size, void* d_ws, size_t ws_size,
                              hipStream_t stream) {
    const float* x = (const float*)d_in[0];
    const float* y = (const float*)d_in[1];
    float* out = (float*)d_out;
    float* ws = (float*)d_ws;

    float* mu    = ws + MU_OFF;
    float* invd  = ws + INVD_OFF;
    float* gmaxp = ws + GMAXP_OFF;
    float* psx   = ws + GMAXP_OFF;            // aliases gmaxp (dead before pass1)
    float* psy   = ws + GMAXP_OFF + 8 * HW;
    float* zp    = ws + ZP_OFF;
    float* accum = ws + ACC_OFF;
    unsigned short* Xb = (unsigned short*)((char*)d_ws + XB_BYTE);
    unsigned short* Yb = (unsigned short*)((char*)d_ws + YB_BYTE);

    hipMemsetAsync(accum, 0, sizeof(float), stream);

    hipLaunchKernelGGL(k_mu, dim3(NC), dim3(256), 0, stream, y, mu);
    hipLaunchKernelGGL(k_sumsq, dim3(HW / 256, NC / 64), dim3(256), 0, stream, x, y, mu, psx, psy);
    hipLaunchKernelGGL(k_transpose, dim3(HW / 64, NC / 64, 2), dim3(256), 0, stream,
                       x, y, mu, psx, psy, Xb, Yb);

    dim3 grid(HW / TI, NCH);
    hipLaunchKernelGGL(k_pass1, grid, dim3(256), 0, stream, Xb, Yb, gmaxp);
    hipLaunchKernelGGL(k_invd, dim3(HW / 256), dim3(256), 0, stream, gmaxp, invd);
    hipLaunchKernelGGL(k_pass2, grid, dim3(256), 0, stream, Xb, Yb, invd, zp);
    hipLaunchKernelGGL(k_kmax, dim3(HW / 256), dim3(256), 0, stream, zp, gmaxp, Xb, Yb, accum);
    hipLaunchKernelGGL(k_final, dim3(1), dim3(1), 0, stream, accum, out);
}

// Round 6
// 172.286 us; speedup vs baseline: 3.2215x; 1.3021x over previous
//
#include <hip/hip_runtime.h>
#include <hip/hip_bf16.h>
#include <math.h>

#define HW 6400
#define NC 512
#define NH 80
#define NW 80
#define NCH 25      // column chunks (blocks in y) for GEMM passes
#define NSLOT 50    // per-row gmax partial slots = NCH * 2
#define NCYS 8      // column chunks for streaming pass2
#define JCH 256     // columns per GEMM block
#define TI 128      // row tile per GEMM block
#define BK 64       // K tile
#define NT16 400    // 16x16 tiles per dimension (6400/16)

typedef __attribute__((ext_vector_type(8))) short short8;
typedef __attribute__((ext_vector_type(4))) float v4f;

// ---- workspace layout (float offsets) ----
#define MU_OFF    0
#define INVD_OFF  512
#define GMAXP_OFF (512 + HW)               // HW*NSLOT; aliased by psx/psy pre-pass1
#define ZP_OFF    (GMAXP_OFF + HW*NSLOT)   // HW*NSLOT (fallback) / HW*NCYS (stream)
#define WDP_OFF   (ZP_OFF + HW*NSLOT)      // HW*NCYS
#define ACC_OFF   (WDP_OFF + HW*NCYS)
#define F32_FLOATS (ACC_OFF + 64)
#define XB_BYTE   ((size_t)(((F32_FLOATS*4) + 255) & ~255))
#define YB_BYTE   (XB_BYTE + (size_t)HW*NC*2)
#define G_BYTE    (YB_BYTE + (size_t)HW*NC*2)
#define G_BYTES   ((size_t)NT16 * NT16 * 256 * 2)   // 81,920,000

__global__ void k_mu(const float* __restrict__ y, float* __restrict__ mu) {
    int c = blockIdx.x;
    const float* yc = y + (size_t)c * HW;
    float s = 0.f;
    for (int i = threadIdx.x; i < HW; i += 256) s += yc[i];
    __shared__ float red[256];
    red[threadIdx.x] = s;
    __syncthreads();
    for (int off = 128; off > 0; off >>= 1) {
        if (threadIdx.x < off) red[threadIdx.x] += red[threadIdx.x + off];
        __syncthreads();
    }
    if (threadIdx.x == 0) mu[c] = red[0] * (1.0f / HW);
}

__global__ void k_sumsq(const float* __restrict__ x, const float* __restrict__ y,
                        const float* __restrict__ mu,
                        float* __restrict__ psx, float* __restrict__ psy) {
    int i = blockIdx.x * 256 + threadIdx.x;
    int c0 = blockIdx.y * 64;
    float sx = 0.f, sy = 0.f;
    for (int c = c0; c < c0 + 64; ++c) {
        float m = mu[c];
        float dx = x[(size_t)c * HW + i] - m;
        float dy = y[(size_t)c * HW + i] - m;
        sx = fmaf(dx, dx, sx);
        sy = fmaf(dy, dy, sy);
    }
    psx[(size_t)blockIdx.y * HW + i] = sx;
    psy[(size_t)blockIdx.y * HW + i] = sy;
}

__global__ void k_transpose(const float* __restrict__ x, const float* __restrict__ y,
                            const float* __restrict__ mu,
                            const float* __restrict__ psx, const float* __restrict__ psy,
                            unsigned short* __restrict__ xb, unsigned short* __restrict__ yb) {
    __shared__ float tile[64 * 68];
    __shared__ float ssinv[64];
    const int t = threadIdx.x;
    const int i0 = blockIdx.x * 64;
    const int c0 = blockIdx.y * 64;
    const int z = blockIdx.z;
    const float* src = z ? y : x;
    const float* ps  = z ? psy : psx;
    unsigned short* dst = z ? yb : xb;

    if (t < 64) {
        float s = 0.f;
        #pragma unroll
        for (int p = 0; p < 8; ++p) s += ps[(size_t)p * HW + i0 + t];
        ssinv[t] = 1.0f / fmaxf(sqrtf(s), 1e-12f);
    }
    __syncthreads();
    #pragma unroll 4
    for (int it = 0; it < 16; ++it) {
        int cl = it * 4 + (t >> 6);
        int il = t & 63;
        float v = (src[(size_t)(c0 + cl) * HW + i0 + il] - mu[c0 + cl]) * ssinv[il];
        tile[il * 68 + cl] = v;
    }
    __syncthreads();
    #pragma unroll
    for (int it = 0; it < 2; ++it) {
        int il = t >> 2;
        int seg = (t & 3) + it * 4;
        unsigned int pk[4];
        #pragma unroll
        for (int p = 0; p < 4; ++p) {
            float v0 = tile[il * 68 + seg * 8 + p * 2];
            float v1 = tile[il * 68 + seg * 8 + p * 2 + 1];
            __hip_bfloat16 h0 = __float2bfloat16(v0);
            __hip_bfloat16 h1 = __float2bfloat16(v1);
            unsigned short u0 = *reinterpret_cast<unsigned short*>(&h0);
            unsigned short u1 = *reinterpret_cast<unsigned short*>(&h1);
            pk[p] = (unsigned int)u0 | ((unsigned int)u1 << 16);
        }
        uint4 val = make_uint4(pk[0], pk[1], pk[2], pk[3]);
        *(uint4*)&dst[(size_t)(i0 + il) * NC + c0 + seg * 8] = val;
    }
}

// MFMA GEMM driver (R5-proven): named-scalar register prefetch (no lambda-
// captured arrays — those fail SROA and spill), swizzled LDS, 0 conflicts.
template <typename F>
__device__ __forceinline__ void gemm_driver(const unsigned short* __restrict__ Xb,
                                            const unsigned short* __restrict__ Yb,
                                            F&& consume) {
    __shared__ char sA[TI * BK * 2];
    __shared__ char sB[TI * BK * 2];
    const int t = threadIdx.x;
    const int w = t >> 6, l = t & 63;
    const int wr = w >> 1, wc = w & 1;
    const int lr = l & 15, lg = l >> 4;
    const int i0 = blockIdx.x * TI;
    const int jbase = blockIdx.y * JCH;

    int aoff[4][2], boff[4][2];
    #pragma unroll
    for (int mt = 0; mt < 4; ++mt) {
        int row = wr * 64 + mt * 16 + lr;
        #pragma unroll
        for (int ks = 0; ks < 2; ++ks) {
            int seg = ks * 4 + lg;
            aoff[mt][ks] = row * 128 + ((seg ^ (row & 7)) * 16);
        }
    }
    #pragma unroll
    for (int nt = 0; nt < 4; ++nt) {
        int row = wc * 64 + nt * 16 + lr;
        #pragma unroll
        for (int ks = 0; ks < 2; ++ks) {
            int seg = ks * 4 + lg;
            boff[nt][ks] = row * 128 + ((seg ^ (row & 7)) * 16);
        }
    }
    const int sr0 = t >> 3,           sr1 = (t + 256) >> 3;
    const int sr2 = (t + 512) >> 3,   sr3 = (t + 768) >> 3;
    const int sg  = t & 7;
    const int sw0 = sr0 * 128 + ((sg ^ (sr0 & 7)) * 16);
    const int sw1 = sr1 * 128 + ((sg ^ (sr1 & 7)) * 16);
    const int sw2 = sr2 * 128 + ((sg ^ (sr2 & 7)) * 16);
    const int sw3 = sr3 * 128 + ((sg ^ (sr3 & 7)) * 16);
    const int sseg8 = sg * 8;

    const unsigned short* pa0 = Xb + (size_t)(i0 + sr0) * NC + sseg8;
    const unsigned short* pa1 = Xb + (size_t)(i0 + sr1) * NC + sseg8;
    const unsigned short* pa2 = Xb + (size_t)(i0 + sr2) * NC + sseg8;
    const unsigned short* pa3 = Xb + (size_t)(i0 + sr3) * NC + sseg8;
    const unsigned short* pb0 = Yb + (size_t)(jbase + sr0) * NC + sseg8;
    const unsigned short* pb1 = Yb + (size_t)(jbase + sr1) * NC + sseg8;
    const unsigned short* pb2 = Yb + (size_t)(jbase + sr2) * NC + sseg8;
    const unsigned short* pb3 = Yb + (size_t)(jbase + sr3) * NC + sseg8;

    uint4 av0, av1, av2, av3, bv0, bv1, bv2, bv3;
    av0 = *(const uint4*)(pa0); av1 = *(const uint4*)(pa1);
    av2 = *(const uint4*)(pa2); av3 = *(const uint4*)(pa3);
    bv0 = *(const uint4*)(pb0); bv1 = *(const uint4*)(pb1);
    bv2 = *(const uint4*)(pb2); bv3 = *(const uint4*)(pb3);

    #pragma unroll 1
    for (int jt = 0; jt < JCH; jt += TI) {
        v4f acc[4][4];
        #pragma unroll
        for (int mt = 0; mt < 4; ++mt)
            #pragma unroll
            for (int nt = 0; nt < 4; ++nt)
                acc[mt][nt] = (v4f){0.f, 0.f, 0.f, 0.f};

        #pragma unroll 1
        for (int kt = 0; kt < NC; kt += BK) {
            __syncthreads();
            *(uint4*)&sA[sw0] = av0; *(uint4*)&sA[sw1] = av1;
            *(uint4*)&sA[sw2] = av2; *(uint4*)&sA[sw3] = av3;
            *(uint4*)&sB[sw0] = bv0; *(uint4*)&sB[sw1] = bv1;
            *(uint4*)&sB[sw2] = bv2; *(uint4*)&sB[sw3] = bv3;
            __syncthreads();
            {
                int nkt = kt + BK, njt = jt;
                if (nkt == NC) { nkt = 0; njt += TI; }
                if (njt >= JCH) { nkt = 0; njt = 0; }
                int ao = nkt;
                int bo = njt * NC + nkt;
                av0 = *(const uint4*)(pa0 + ao); av1 = *(const uint4*)(pa1 + ao);
                av2 = *(const uint4*)(pa2 + ao); av3 = *(const uint4*)(pa3 + ao);
                bv0 = *(const uint4*)(pb0 + bo); bv1 = *(const uint4*)(pb1 + bo);
                bv2 = *(const uint4*)(pb2 + bo); bv3 = *(const uint4*)(pb3 + bo);
            }
            #pragma unroll
            for (int ks = 0; ks < 2; ++ks) {
                short8 af[4], bf[4];
                #pragma unroll
                for (int mt = 0; mt < 4; ++mt) af[mt] = *(const short8*)&sA[aoff[mt][ks]];
                #pragma unroll
                for (int nt = 0; nt < 4; ++nt) bf[nt] = *(const short8*)&sB[boff[nt][ks]];
                #pragma unroll
                for (int mt = 0; mt < 4; ++mt)
                    #pragma unroll
                    for (int nt = 0; nt < 4; ++nt)
                        acc[mt][nt] = __builtin_amdgcn_mfma_f32_16x16x32_bf16(
                            af[mt], bf[nt], acc[mt][nt], 0, 0, 0);
            }
        }
        consume(acc, jt);
    }
}

__device__ __forceinline__ void rmax_epilogue(float (&rmax)[16], float* gmaxp,
                                              int i0, int wr, int wc, int lr, int lg) {
    #pragma unroll
    for (int u = 0; u < 16; ++u) {
        float v = rmax[u];
        v = fmaxf(v, __shfl_xor(v, 1));
        v = fmaxf(v, __shfl_xor(v, 2));
        v = fmaxf(v, __shfl_xor(v, 4));
        v = fmaxf(v, __shfl_xor(v, 8));
        if (lr == 0) {
            int row = i0 + wr * 64 + (u >> 2) * 16 + lg * 4 + (u & 3);
            gmaxp[(size_t)row * NSLOT + blockIdx.y * 2 + wc] = v;
        }
    }
}

// pass1 with G store: row-max partials + packed-bf16 tile store of G.
// Tile storage: G[rt][ct][lane*4 + reg] — one coalesced dwordx2 per lane.
__global__ __launch_bounds__(256, 2) void k_pass1s(const unsigned short* __restrict__ Xb,
                                                   const unsigned short* __restrict__ Yb,
                                                   float* __restrict__ gmaxp,
                                                   unsigned int* __restrict__ G2) {
    const int t = threadIdx.x;
    const int w = t >> 6, l = t & 63;
    const int wr = w >> 1, wc = w & 1;
    const int lr = l & 15, lg = l >> 4;
    const int i0 = blockIdx.x * TI;
    const int jbase = blockIdx.y * JCH;
    float rmax[16];
    #pragma unroll
    for (int u = 0; u < 16; ++u) rmax[u] = -3.0e38f;

    gemm_driver(Xb, Yb, [&](v4f (&acc)[4][4], int jt) {
        #pragma unroll
        for (int mt = 0; mt < 4; ++mt) {
            size_t rbase = (size_t)(i0 / 16 + wr * 4 + mt) * (NT16 * 128);  // uint2 units
            #pragma unroll
            for (int nt = 0; nt < 4; ++nt) {
                int ct = (jbase + jt) / 16 + wc * 4 + nt;
                unsigned int pk0, pk1;
                {
                    __hip_bfloat16 h0 = __float2bfloat16(acc[mt][nt][0]);
                    __hip_bfloat16 h1 = __float2bfloat16(acc[mt][nt][1]);
                    __hip_bfloat16 h2 = __float2bfloat16(acc[mt][nt][2]);
                    __hip_bfloat16 h3 = __float2bfloat16(acc[mt][nt][3]);
                    pk0 = (unsigned int)*(unsigned short*)&h0 | ((unsigned int)*(unsigned short*)&h1 << 16);
                    pk1 = (unsigned int)*(unsigned short*)&h2 | ((unsigned int)*(unsigned short*)&h3 << 16);
                }
                *(uint2*)&G2[(rbase + (size_t)ct * 128 + l * 2)] = make_uint2(pk0, pk1);
                #pragma unroll
                for (int r = 0; r < 4; ++r)
                    rmax[mt * 4 + r] = fmaxf(rmax[mt * 4 + r], acc[mt][nt][r]);
            }
        }
    });
    rmax_epilogue(rmax, gmaxp, i0, wr, wc, lr, lg);
}

// streaming pass2: read stored G tiles, inline dmin, exp-sum Z + diag weight.
// wave w handles row-tile rt over a 50-col-tile chunk cy.
__global__ __launch_bounds__(256) void k_pass2s(const unsigned int* __restrict__ G2,
                                                const float* __restrict__ gmaxp,
                                                float* __restrict__ zp,
                                                float* __restrict__ wdp) {
    const int t = threadIdx.x;
    const int w = t >> 6, l = t & 63;
    const int lr = l & 15, lg = l >> 4;
    const int rt = blockIdx.x * 4 + w;
    const int cy = blockIdx.y;

    // inline invd for the 16 rows of this row-tile
    float m = -3.0e38f;
    {
        int row = rt * 16 + lr;
        #pragma unroll
        for (int k = 0; k < 13; ++k) {
            int s = lg + 4 * k;
            if (s < NSLOT) m = fmaxf(m, gmaxp[(size_t)row * NSLOT + s]);
        }
        m = fmaxf(m, __shfl_xor(m, 16));
        m = fmaxf(m, __shfl_xor(m, 32));
    }
    float inv_lr = 1.0f / ((1.0f - m) + 1e-5f);   // inv for row rt*16+lr
    float c1[4], c2[4];
    #pragma unroll
    for (int r = 0; r < 4; ++r) {
        float iv = __shfl(inv_lr, lg * 4 + r);
        c2[r] = 2.0f * iv;
        c1[r] = 2.0f - 2.0f * iv;
    }

    const uint2* base = (const uint2*)G2 + (size_t)rt * (NT16 * 64) + l;
    float zs[4] = {0.f, 0.f, 0.f, 0.f};
    #pragma unroll 4
    for (int ct = cy * 50; ct < cy * 50 + 50; ++ct) {
        uint2 v = base[(size_t)ct * 64];
        float g0 = __uint_as_float((v.x & 0xFFFFu) << 16);
        float g1 = __uint_as_float(v.x & 0xFFFF0000u);
        float g2 = __uint_as_float((v.y & 0xFFFFu) << 16);
        float g3 = __uint_as_float(v.y & 0xFFFF0000u);
        zs[0] += __expf(fmaf(c2[0], g0, c1[0]));
        zs[1] += __expf(fmaf(c2[1], g1, c1[1]));
        zs[2] += __expf(fmaf(c2[2], g2, c1[2]));
        zs[3] += __expf(fmaf(c2[3], g3, c1[3]));
    }
    // diagonal weight (tile ct == rt lives in chunk rt/50)
    float wd[4] = {0.f, 0.f, 0.f, 0.f};
    if (rt / 50 == cy) {
        uint2 v = base[(size_t)rt * 64];
        float g[4];
        g[0] = __uint_as_float((v.x & 0xFFFFu) << 16);
        g[1] = __uint_as_float(v.x & 0xFFFF0000u);
        g[2] = __uint_as_float((v.y & 0xFFFFu) << 16);
        g[3] = __uint_as_float(v.y & 0xFFFF0000u);
        #pragma unroll
        for (int r = 0; r < 4; ++r)
            if (lr == lg * 4 + r) wd[r] = __expf(fmaf(c2[r], g[r], c1[r]));
    }
    #pragma unroll
    for (int r = 0; r < 4; ++r) {
        float z = zs[r], d = wd[r];
        z += __shfl_xor(z, 1);  d += __shfl_xor(d, 1);
        z += __shfl_xor(z, 2);  d += __shfl_xor(d, 2);
        z += __shfl_xor(z, 4);  d += __shfl_xor(d, 4);
        z += __shfl_xor(z, 8);  d += __shfl_xor(d, 8);
        if (lr == 0) {
            int row = rt * 16 + lg * 4 + r;
            zp[(size_t)row * NCYS + cy] = z;
            wdp[(size_t)row * NCYS + cy] = d;
        }
    }
}

__global__ void k_kmax_s(const float* __restrict__ zp, const float* __restrict__ wdp,
                         const float* __restrict__ gmaxp, float* __restrict__ accum,
                         int* __restrict__ counter, float* __restrict__ out) {
    int i = blockIdx.x * 256 + threadIdx.x;
    float Z = 0.f, wd = 0.f, gmax = -3.0e38f;
    #pragma unroll
    for (int s = 0; s < NCYS; ++s) {
        Z += zp[(size_t)i * NCYS + s];
        wd += wdp[(size_t)i * NCYS + s];
    }
    #pragma unroll
    for (int s = 0; s < NSLOT; ++s) gmax = fmaxf(gmax, gmaxp[(size_t)i * NSLOT + s]);
    float dmin = 1.0f - gmax;
    float inv = 1.0f / (dmin + 1e-5f);
    float wmx = __expf(2.0f - 2.0f * dmin * inv);
    float invZ = 1.0f / Z;
    float kmax = fmaxf(0.9f * wmx * invZ, 0.9f * wd * invZ + 0.1f);

    __shared__ float red[256];
    red[threadIdx.x] = kmax;
    __syncthreads();
    for (int off = 128; off > 0; off >>= 1) {
        if (threadIdx.x < off) red[threadIdx.x] += red[threadIdx.x + off];
        __syncthreads();
    }
    if (threadIdx.x == 0) {
        atomicAdd(accum, red[0]);
        __threadfence();
        int n = atomicAdd(counter, 1);
        if (n == (int)gridDim.x - 1) {
            float total = atomicAdd(accum, 0.0f);
            out[0] = -logf(total * (1.0f / HW) + 1e-5f);
        }
    }
}

// ---------- fallback path (ws too small for G): R5 two-GEMM ----------
__global__ __launch_bounds__(256, 2) void k_pass1(const unsigned short* __restrict__ Xb,
                                                  const unsigned short* __restrict__ Yb,
                                                  float* __restrict__ gmaxp) {
    const int t = threadIdx.x;
    const int w = t >> 6, l = t & 63;
    const int wr = w >> 1, wc = w & 1;
    const int lr = l & 15, lg = l >> 4;
    const int i0 = blockIdx.x * TI;
    float rmax[16];
    #pragma unroll
    for (int u = 0; u < 16; ++u) rmax[u] = -3.0e38f;
    gemm_driver(Xb, Yb, [&](v4f (&acc)[4][4], int jt) {
        (void)jt;
        #pragma unroll
        for (int mt = 0; mt < 4; ++mt)
            #pragma unroll
            for (int r = 0; r < 4; ++r) {
                float mm = acc[mt][0][r];
                #pragma unroll
                for (int nt = 1; nt < 4; ++nt) mm = fmaxf(mm, acc[mt][nt][r]);
                rmax[mt * 4 + r] = fmaxf(rmax[mt * 4 + r], mm);
            }
    });
    rmax_epilogue(rmax, gmaxp, i0, wr, wc, lr, lg);
}

__global__ void k_invd(const float* __restrict__ gmaxp, float* __restrict__ invd) {
    int i = blockIdx.x * 256 + threadIdx.x;
    float m = -3.0e38f;
    #pragma unroll
    for (int s = 0; s < NSLOT; ++s) m = fmaxf(m, gmaxp[(size_t)i * NSLOT + s]);
    invd[i] = 1.0f / ((1.0f - m) + 1e-5f);
}

__global__ __launch_bounds__(256, 2) void k_pass2(const unsigned short* __restrict__ Xb,
                                                  const unsigned short* __restrict__ Yb,
                                                  const float* __restrict__ invd,
                                                  float* __restrict__ zp) {
    const int t = threadIdx.x;
    const int w = t >> 6, l = t & 63;
    const int wr = w >> 1, wc = w & 1;
    const int lr = l & 15, lg = l >> 4;
    const int i0 = blockIdx.x * TI;
    float zs[16], c1[16], c2[16];
    #pragma unroll
    for (int u = 0; u < 16; ++u) {
        int row = i0 + wr * 64 + (u >> 2) * 16 + lg * 4 + (u & 3);
        float inv = invd[row];
        c2[u] = 2.0f * inv;
        c1[u] = 2.0f - 2.0f * inv;
        zs[u] = 0.f;
    }
    gemm_driver(Xb, Yb, [&](v4f (&acc)[4][4], int jt) {
        (void)jt;
        #pragma unroll
        for (int mt = 0; mt < 4; ++mt)
            #pragma unroll
            for (int r = 0; r < 4; ++r) {
                int u = mt * 4 + r;
                float s = 0.f;
                #pragma unroll
                for (int nt = 0; nt < 4; ++nt)
                    s += __expf(fmaf(c2[u], acc[mt][nt][r], c1[u]));
                zs[u] += s;
            }
    });
    #pragma unroll
    for (int u = 0; u < 16; ++u) {
        float z = zs[u];
        z += __shfl_xor(z, 1);
        z += __shfl_xor(z, 2);
        z += __shfl_xor(z, 4);
        z += __shfl_xor(z, 8);
        if (lr == 0) {
            int row = i0 + wr * 64 + (u >> 2) * 16 + lg * 4 + (u & 3);
            zp[(size_t)row * NSLOT + blockIdx.y * 2 + wc] = z;
        }
    }
}

__global__ void k_kmax(const float* __restrict__ zp, const float* __restrict__ gmaxp,
                       const unsigned short* __restrict__ Xb, const unsigned short* __restrict__ Yb,
                       float* __restrict__ accum, int* __restrict__ counter,
                       float* __restrict__ out) {
    int i = blockIdx.x * 256 + threadIdx.x;
    float Z = 0.f, gmax = -3.0e38f;
    #pragma unroll
    for (int s = 0; s < NSLOT; ++s) {
        Z += zp[(size_t)i * NSLOT + s];
        gmax = fmaxf(gmax, gmaxp[(size_t)i * NSLOT + s]);
    }
    float gii = 0.f;
    const uint2* xr = (const uint2*)(Xb + (size_t)i * NC);
    const uint2* yr = (const uint2*)(Yb + (size_t)i * NC);
    for (int c4 = 0; c4 < NC / 4; ++c4) {
        uint2 xa = xr[c4], ya = yr[c4];
        float x0 = __uint_as_float((xa.x & 0xFFFFu) << 16), y0 = __uint_as_float((ya.x & 0xFFFFu) << 16);
        float x1 = __uint_as_float(xa.x & 0xFFFF0000u),     y1 = __uint_as_float(ya.x & 0xFFFF0000u);
        float x2 = __uint_as_float((xa.y & 0xFFFFu) << 16), y2 = __uint_as_float((ya.y & 0xFFFFu) << 16);
        float x3 = __uint_as_float(xa.y & 0xFFFF0000u),     y3 = __uint_as_float(ya.y & 0xFFFF0000u);
        gii = fmaf(x0, y0, gii); gii = fmaf(x1, y1, gii);
        gii = fmaf(x2, y2, gii); gii = fmaf(x3, y3, gii);
    }
    float dmin = 1.0f - gmax;
    float inv = 1.0f / (dmin + 1e-5f);
    float wmx = __expf(2.0f - 2.0f * dmin * inv);
    float wii = __expf(2.0f - 2.0f * (1.0f - gii) * inv);
    float invZ = 1.0f / Z;
    float kmax = fmaxf(0.9f * wmx * invZ, 0.9f * wii * invZ + 0.1f);

    __shared__ float red[256];
    red[threadIdx.x] = kmax;
    __syncthreads();
    for (int off = 128; off > 0; off >>= 1) {
        if (threadIdx.x < off) red[threadIdx.x] += red[threadIdx.x + off];
        __syncthreads();
    }
    if (threadIdx.x == 0) {
        atomicAdd(accum, red[0]);
        __threadfence();
        int n = atomicAdd(counter, 1);
        if (n == (int)gridDim.x - 1) {
            float total = atomicAdd(accum, 0.0f);
            out[0] = -logf(total * (1.0f / HW) + 1e-5f);
        }
    }
}

extern "C" void kernel_launch(void* const* d_in, const int* in_sizes, int n_in,
                              void* d_out, int out_size, void* d_ws, size_t ws_size,
                              hipStream_t stream) {
    const float* x = (const float*)d_in[0];
    const float* y = (const float*)d_in[1];
    float* out = (float*)d_out;
    float* ws = (float*)d_ws;

    float* mu    = ws + MU_OFF;
    float* invd  = ws + INVD_OFF;
    float* gmaxp = ws + GMAXP_OFF;
    float* psx   = ws + GMAXP_OFF;            // aliases gmaxp (dead before pass1)
    float* psy   = ws + GMAXP_OFF + 8 * HW;
    float* zp    = ws + ZP_OFF;
    float* wdp   = ws + WDP_OFF;
    float* accum = ws + ACC_OFF;
    int*   counter = (int*)(accum + 1);
    unsigned short* Xb = (unsigned short*)((char*)d_ws + XB_BYTE);
    unsigned short* Yb = (unsigned short*)((char*)d_ws + YB_BYTE);
    unsigned int*   G2 = (unsigned int*)((char*)d_ws + G_BYTE);

    const bool bigws = ws_size >= (G_BYTE + G_BYTES);

    hipMemsetAsync(accum, 0, 8, stream);

    hipLaunchKernelGGL(k_mu, dim3(NC), dim3(256), 0, stream, y, mu);
    hipLaunchKernelGGL(k_sumsq, dim3(HW / 256, NC / 64), dim3(256), 0, stream, x, y, mu, psx, psy);
    hipLaunchKernelGGL(k_transpose, dim3(HW / 64, NC / 64, 2), dim3(256), 0, stream,
                       x, y, mu, psx, psy, Xb, Yb);

    dim3 grid(HW / TI, NCH);
    if (bigws) {
        hipLaunchKernelGGL(k_pass1s, grid, dim3(256), 0, stream, Xb, Yb, gmaxp, G2);
        hipLaunchKernelGGL(k_pass2s, dim3(NT16 / 4, NCYS), dim3(256), 0, stream, G2, gmaxp, zp, wdp);
        hipLaunchKernelGGL(k_kmax_s, dim3(HW / 256), dim3(256), 0, stream, zp, wdp, gmaxp,
                           accum, counter, out);
    } else {
        hipLaunchKernelGGL(k_pass1, grid, dim3(256), 0, stream, Xb, Yb, gmaxp);
        hipLaunchKernelGGL(k_invd, dim3(HW / 256), dim3(256), 0, stream, gmaxp, invd);
        hipLaunchKernelGGL(k_pass2, grid, dim3(256), 0, stream, Xb, Yb, invd, zp);
        hipLaunchKernelGGL(k_kmax, dim3(HW / 256), dim3(256), 0, stream, zp, gmaxp, Xb, Yb,
                           accum, counter, out);
    }
}

// Round 7
// 166.200 us; speedup vs baseline: 3.3395x; 1.0366x over previous
//
#include <hip/hip_runtime.h>
#include <hip/hip_bf16.h>
#include <math.h>

#define HW 6400
#define NC 512
#define NH 80
#define NW 80
#define NCH 25      // column chunks (blocks in y) for GEMM passes
#define NSLOT 50    // per-row gmax partial slots = NCH * 2
#define NCYS 8      // column chunks for streaming pass2
#define JCH 256     // columns per GEMM block
#define TI 128      // row tile per GEMM block
#define BK 64       // K tile
#define NT16 400    // 16x16 tiles per dimension (6400/16)

typedef __attribute__((ext_vector_type(8))) short short8;
typedef __attribute__((ext_vector_type(4))) float v4f;

// ---- workspace layout (float offsets) ----
#define MU_OFF    0
#define INVD_OFF  512
#define GMAXP_OFF (512 + HW)               // HW*NSLOT; aliased by psx/psy pre-pass1
#define ZP_OFF    (GMAXP_OFF + HW*NSLOT)   // HW*NSLOT (fallback) / HW*NCYS (stream)
#define WDP_OFF   (ZP_OFF + HW*NSLOT)      // HW*NCYS
#define ACC_OFF   (WDP_OFF + HW*NCYS)
#define F32_FLOATS (ACC_OFF + 64)
#define XB_BYTE   ((size_t)(((F32_FLOATS*4) + 255) & ~255))
#define YB_BYTE   (XB_BYTE + (size_t)HW*NC*2)
#define G_BYTE    (YB_BYTE + (size_t)HW*NC*2)
#define G_BYTES   ((size_t)NT16 * NT16 * 256 * 2)   // 81,920,000

// async global->LDS, 16 B per lane, LDS dest = wave-uniform base + lane*16
typedef __attribute__((address_space(1))) unsigned int uint_g;
typedef __attribute__((address_space(3))) unsigned int uint_l;
__device__ __forceinline__ void gload16(const void* g, void* l) {
    __builtin_amdgcn_global_load_lds((const uint_g*)g, (uint_l*)l, 16, 0, 0);
}

__global__ void k_mu(const float* __restrict__ y, float* __restrict__ mu) {
    int c = blockIdx.x;
    const float* yc = y + (size_t)c * HW;
    float s = 0.f;
    for (int i = threadIdx.x; i < HW; i += 256) s += yc[i];
    __shared__ float red[256];
    red[threadIdx.x] = s;
    __syncthreads();
    for (int off = 128; off > 0; off >>= 1) {
        if (threadIdx.x < off) red[threadIdx.x] += red[threadIdx.x + off];
        __syncthreads();
    }
    if (threadIdx.x == 0) mu[c] = red[0] * (1.0f / HW);
}

__global__ void k_sumsq(const float* __restrict__ x, const float* __restrict__ y,
                        const float* __restrict__ mu,
                        float* __restrict__ psx, float* __restrict__ psy) {
    int i = blockIdx.x * 256 + threadIdx.x;
    int c0 = blockIdx.y * 64;
    float sx = 0.f, sy = 0.f;
    for (int c = c0; c < c0 + 64; ++c) {
        float m = mu[c];
        float dx = x[(size_t)c * HW + i] - m;
        float dy = y[(size_t)c * HW + i] - m;
        sx = fmaf(dx, dx, sx);
        sy = fmaf(dy, dy, sy);
    }
    psx[(size_t)blockIdx.y * HW + i] = sx;
    psy[(size_t)blockIdx.y * HW + i] = sy;
}

__global__ void k_transpose(const float* __restrict__ x, const float* __restrict__ y,
                            const float* __restrict__ mu,
                            const float* __restrict__ psx, const float* __restrict__ psy,
                            unsigned short* __restrict__ xb, unsigned short* __restrict__ yb) {
    __shared__ float tile[64 * 68];
    __shared__ float ssinv[64];
    const int t = threadIdx.x;
    const int i0 = blockIdx.x * 64;
    const int c0 = blockIdx.y * 64;
    const int z = blockIdx.z;
    const float* src = z ? y : x;
    const float* ps  = z ? psy : psx;
    unsigned short* dst = z ? yb : xb;

    if (t < 64) {
        float s = 0.f;
        #pragma unroll
        for (int p = 0; p < 8; ++p) s += ps[(size_t)p * HW + i0 + t];
        ssinv[t] = 1.0f / fmaxf(sqrtf(s), 1e-12f);
    }
    __syncthreads();
    #pragma unroll 4
    for (int it = 0; it < 16; ++it) {
        int cl = it * 4 + (t >> 6);
        int il = t & 63;
        float v = (src[(size_t)(c0 + cl) * HW + i0 + il] - mu[c0 + cl]) * ssinv[il];
        tile[il * 68 + cl] = v;
    }
    __syncthreads();
    #pragma unroll
    for (int it = 0; it < 2; ++it) {
        int il = t >> 2;
        int seg = (t & 3) + it * 4;
        unsigned int pk[4];
        #pragma unroll
        for (int p = 0; p < 4; ++p) {
            float v0 = tile[il * 68 + seg * 8 + p * 2];
            float v1 = tile[il * 68 + seg * 8 + p * 2 + 1];
            __hip_bfloat16 h0 = __float2bfloat16(v0);
            __hip_bfloat16 h1 = __float2bfloat16(v1);
            unsigned short u0 = *reinterpret_cast<unsigned short*>(&h0);
            unsigned short u1 = *reinterpret_cast<unsigned short*>(&h1);
            pk[p] = (unsigned int)u0 | ((unsigned int)u1 << 16);
        }
        uint4 val = make_uint4(pk[0], pk[1], pk[2], pk[3]);
        *(uint4*)&dst[(size_t)(i0 + il) * NC + c0 + seg * 8] = val;
    }
}

// MFMA GEMM driver, m97-style async staging: global_load_lds width-16, no VGPR
// round trip. XOR swizzle baked into each lane's GLOBAL source address (LDS dest
// is wave-uniform base + lane*16); ds_read side keeps the swizzled offsets and
// stays conflict-free. Wave w stages rows [w*32, w*32+32) of both tiles.
template <typename F>
__device__ __forceinline__ void gemm_driver(const unsigned short* __restrict__ Xb,
                                            const unsigned short* __restrict__ Yb,
                                            F&& consume) {
    __shared__ char sA[TI * BK * 2];   // [row][k], 128 B/row, seg^(row&7) swizzle
    __shared__ char sB[TI * BK * 2];
    const int t = threadIdx.x;
    const int w = t >> 6, l = t & 63;
    const int wr = w >> 1, wc = w & 1;
    const int lr = l & 15, lg = l >> 4;
    const int i0 = blockIdx.x * TI;
    const int jbase = blockIdx.y * JCH;

    int aoff[4][2], boff[4][2];
    #pragma unroll
    for (int mt = 0; mt < 4; ++mt) {
        int row = wr * 64 + mt * 16 + lr;
        #pragma unroll
        for (int ks = 0; ks < 2; ++ks) {
            int seg = ks * 4 + lg;
            aoff[mt][ks] = row * 128 + ((seg ^ (row & 7)) * 16);
        }
    }
    #pragma unroll
    for (int nt = 0; nt < 4; ++nt) {
        int row = wc * 64 + nt * 16 + lr;
        #pragma unroll
        for (int ks = 0; ks < 2; ++ks) {
            int seg = ks * 4 + lg;
            boff[nt][ks] = row * 128 + ((seg ^ (row & 7)) * 16);
        }
    }

    // staging source geometry: lane l covers LDS slot (w*4+it)*1024 + l*16,
    // i.e. row = w*32 + it*8 + (l>>3), k-seg = ((l&7) ^ (l>>3)) * 8
    const int strow = l >> 3;
    const int stcol = ((l & 7) ^ strow) * 8;
    char* dA0 = sA + (w * 4 + 0) * 1024;
    char* dA1 = sA + (w * 4 + 1) * 1024;
    char* dA2 = sA + (w * 4 + 2) * 1024;
    char* dA3 = sA + (w * 4 + 3) * 1024;
    char* dB0 = sB + (w * 4 + 0) * 1024;
    char* dB1 = sB + (w * 4 + 1) * 1024;
    char* dB2 = sB + (w * 4 + 2) * 1024;
    char* dB3 = sB + (w * 4 + 3) * 1024;
    const unsigned short* ga = Xb + (size_t)(i0 + w * 32 + strow) * NC + stcol;
    const unsigned short* gb0 = Yb + (size_t)(jbase + w * 32 + strow) * NC + stcol;

    #pragma unroll 1
    for (int jt = 0; jt < JCH; jt += TI) {
        const unsigned short* gb = gb0 + (size_t)jt * NC;
        v4f acc[4][4];
        #pragma unroll
        for (int mt = 0; mt < 4; ++mt)
            #pragma unroll
            for (int nt = 0; nt < 4; ++nt)
                acc[mt][nt] = (v4f){0.f, 0.f, 0.f, 0.f};

        #pragma unroll 1
        for (int kt = 0; kt < NC; kt += BK) {
            __syncthreads();   // previous tile's reads complete before overwrite
            gload16(ga + kt,           dA0);
            gload16(ga + 8  * NC + kt, dA1);
            gload16(ga + 16 * NC + kt, dA2);
            gload16(ga + 24 * NC + kt, dA3);
            gload16(gb + kt,           dB0);
            gload16(gb + 8  * NC + kt, dB1);
            gload16(gb + 16 * NC + kt, dB2);
            gload16(gb + 24 * NC + kt, dB3);
            __syncthreads();   // vmcnt(0) drain -> staged data visible
            #pragma unroll
            for (int ks = 0; ks < 2; ++ks) {
                short8 af[4], bf[4];
                #pragma unroll
                for (int mt = 0; mt < 4; ++mt) af[mt] = *(const short8*)&sA[aoff[mt][ks]];
                #pragma unroll
                for (int nt = 0; nt < 4; ++nt) bf[nt] = *(const short8*)&sB[boff[nt][ks]];
                #pragma unroll
                for (int mt = 0; mt < 4; ++mt)
                    #pragma unroll
                    for (int nt = 0; nt < 4; ++nt)
                        acc[mt][nt] = __builtin_amdgcn_mfma_f32_16x16x32_bf16(
                            af[mt], bf[nt], acc[mt][nt], 0, 0, 0);
            }
        }
        consume(acc, jt);
    }
}

__device__ __forceinline__ void rmax_epilogue(float (&rmax)[16], float* gmaxp,
                                              int i0, int wr, int wc, int lr, int lg) {
    #pragma unroll
    for (int u = 0; u < 16; ++u) {
        float v = rmax[u];
        v = fmaxf(v, __shfl_xor(v, 1));
        v = fmaxf(v, __shfl_xor(v, 2));
        v = fmaxf(v, __shfl_xor(v, 4));
        v = fmaxf(v, __shfl_xor(v, 8));
        if (lr == 0) {
            int row = i0 + wr * 64 + (u >> 2) * 16 + lg * 4 + (u & 3);
            gmaxp[(size_t)row * NSLOT + blockIdx.y * 2 + wc] = v;
        }
    }
}

// pass1 with G store: row-max partials + packed-bf16 tile store of G.
__global__ __launch_bounds__(256, 2) void k_pass1s(const unsigned short* __restrict__ Xb,
                                                   const unsigned short* __restrict__ Yb,
                                                   float* __restrict__ gmaxp,
                                                   unsigned int* __restrict__ G2) {
    const int t = threadIdx.x;
    const int w = t >> 6, l = t & 63;
    const int wr = w >> 1, wc = w & 1;
    const int lr = l & 15, lg = l >> 4;
    const int i0 = blockIdx.x * TI;
    const int jbase = blockIdx.y * JCH;
    float rmax[16];
    #pragma unroll
    for (int u = 0; u < 16; ++u) rmax[u] = -3.0e38f;

    gemm_driver(Xb, Yb, [&](v4f (&acc)[4][4], int jt) {
        #pragma unroll
        for (int mt = 0; mt < 4; ++mt) {
            size_t rbase = (size_t)(i0 / 16 + wr * 4 + mt) * (NT16 * 128);  // uint units
            #pragma unroll
            for (int nt = 0; nt < 4; ++nt) {
                int ct = (jbase + jt) / 16 + wc * 4 + nt;
                unsigned int pk0, pk1;
                {
                    __hip_bfloat16 h0 = __float2bfloat16(acc[mt][nt][0]);
                    __hip_bfloat16 h1 = __float2bfloat16(acc[mt][nt][1]);
                    __hip_bfloat16 h2 = __float2bfloat16(acc[mt][nt][2]);
                    __hip_bfloat16 h3 = __float2bfloat16(acc[mt][nt][3]);
                    pk0 = (unsigned int)*(unsigned short*)&h0 | ((unsigned int)*(unsigned short*)&h1 << 16);
                    pk1 = (unsigned int)*(unsigned short*)&h2 | ((unsigned int)*(unsigned short*)&h3 << 16);
                }
                *(uint2*)&G2[(rbase + (size_t)ct * 128 + l * 2)] = make_uint2(pk0, pk1);
                #pragma unroll
                for (int r = 0; r < 4; ++r)
                    rmax[mt * 4 + r] = fmaxf(rmax[mt * 4 + r], acc[mt][nt][r]);
            }
        }
    });
    rmax_epilogue(rmax, gmaxp, i0, wr, wc, lr, lg);
}

// streaming pass2: read stored G tiles, inline dmin, exp-sum Z + diag weight.
__global__ __launch_bounds__(256) void k_pass2s(const unsigned int* __restrict__ G2,
                                                const float* __restrict__ gmaxp,
                                                float* __restrict__ zp,
                                                float* __restrict__ wdp) {
    const int t = threadIdx.x;
    const int w = t >> 6, l = t & 63;
    const int lr = l & 15, lg = l >> 4;
    const int rt = blockIdx.x * 4 + w;
    const int cy = blockIdx.y;

    float m = -3.0e38f;
    {
        int row = rt * 16 + lr;
        #pragma unroll
        for (int k = 0; k < 13; ++k) {
            int s = lg + 4 * k;
            if (s < NSLOT) m = fmaxf(m, gmaxp[(size_t)row * NSLOT + s]);
        }
        m = fmaxf(m, __shfl_xor(m, 16));
        m = fmaxf(m, __shfl_xor(m, 32));
    }
    float inv_lr = 1.0f / ((1.0f - m) + 1e-5f);
    float c1[4], c2[4];
    #pragma unroll
    for (int r = 0; r < 4; ++r) {
        float iv = __shfl(inv_lr, lg * 4 + r);
        c2[r] = 2.0f * iv;
        c1[r] = 2.0f - 2.0f * iv;
    }

    const uint2* base = (const uint2*)G2 + (size_t)rt * (NT16 * 64) + l;
    float zs[4] = {0.f, 0.f, 0.f, 0.f};
    #pragma unroll 4
    for (int ct = cy * 50; ct < cy * 50 + 50; ++ct) {
        uint2 v = base[(size_t)ct * 64];
        float g0 = __uint_as_float((v.x & 0xFFFFu) << 16);
        float g1 = __uint_as_float(v.x & 0xFFFF0000u);
        float g2 = __uint_as_float((v.y & 0xFFFFu) << 16);
        float g3 = __uint_as_float(v.y & 0xFFFF0000u);
        zs[0] += __expf(fmaf(c2[0], g0, c1[0]));
        zs[1] += __expf(fmaf(c2[1], g1, c1[1]));
        zs[2] += __expf(fmaf(c2[2], g2, c1[2]));
        zs[3] += __expf(fmaf(c2[3], g3, c1[3]));
    }
    float wd[4] = {0.f, 0.f, 0.f, 0.f};
    if (rt / 50 == cy) {
        uint2 v = base[(size_t)rt * 64];
        float g[4];
        g[0] = __uint_as_float((v.x & 0xFFFFu) << 16);
        g[1] = __uint_as_float(v.x & 0xFFFF0000u);
        g[2] = __uint_as_float((v.y & 0xFFFFu) << 16);
        g[3] = __uint_as_float(v.y & 0xFFFF0000u);
        #pragma unroll
        for (int r = 0; r < 4; ++r)
            if (lr == lg * 4 + r) wd[r] = __expf(fmaf(c2[r], g[r], c1[r]));
    }
    #pragma unroll
    for (int r = 0; r < 4; ++r) {
        float z = zs[r], d = wd[r];
        z += __shfl_xor(z, 1);  d += __shfl_xor(d, 1);
        z += __shfl_xor(z, 2);  d += __shfl_xor(d, 2);
        z += __shfl_xor(z, 4);  d += __shfl_xor(d, 4);
        z += __shfl_xor(z, 8);  d += __shfl_xor(d, 8);
        if (lr == 0) {
            int row = rt * 16 + lg * 4 + r;
            zp[(size_t)row * NCYS + cy] = z;
            wdp[(size_t)row * NCYS + cy] = d;
        }
    }
}

__global__ void k_kmax_s(const float* __restrict__ zp, const float* __restrict__ wdp,
                         const float* __restrict__ gmaxp, float* __restrict__ accum,
                         int* __restrict__ counter, float* __restrict__ out) {
    int i = blockIdx.x * 256 + threadIdx.x;
    float Z = 0.f, wd = 0.f, gmax = -3.0e38f;
    #pragma unroll
    for (int s = 0; s < NCYS; ++s) {
        Z += zp[(size_t)i * NCYS + s];
        wd += wdp[(size_t)i * NCYS + s];
    }
    #pragma unroll
    for (int s = 0; s < NSLOT; ++s) gmax = fmaxf(gmax, gmaxp[(size_t)i * NSLOT + s]);
    float dmin = 1.0f - gmax;
    float inv = 1.0f / (dmin + 1e-5f);
    float wmx = __expf(2.0f - 2.0f * dmin * inv);
    float invZ = 1.0f / Z;
    float kmax = fmaxf(0.9f * wmx * invZ, 0.9f * wd * invZ + 0.1f);

    __shared__ float red[256];
    red[threadIdx.x] = kmax;
    __syncthreads();
    for (int off = 128; off > 0; off >>= 1) {
        if (threadIdx.x < off) red[threadIdx.x] += red[threadIdx.x + off];
        __syncthreads();
    }
    if (threadIdx.x == 0) {
        atomicAdd(accum, red[0]);
        __threadfence();
        int n = atomicAdd(counter, 1);
        if (n == (int)gridDim.x - 1) {
            float total = atomicAdd(accum, 0.0f);
            out[0] = -logf(total * (1.0f / HW) + 1e-5f);
        }
    }
}

// ---------- fallback path (ws too small for G): two-GEMM ----------
__global__ __launch_bounds__(256, 2) void k_pass1(const unsigned short* __restrict__ Xb,
                                                  const unsigned short* __restrict__ Yb,
                                                  float* __restrict__ gmaxp) {
    const int t = threadIdx.x;
    const int w = t >> 6, l = t & 63;
    const int wr = w >> 1, wc = w & 1;
    const int lr = l & 15, lg = l >> 4;
    const int i0 = blockIdx.x * TI;
    float rmax[16];
    #pragma unroll
    for (int u = 0; u < 16; ++u) rmax[u] = -3.0e38f;
    gemm_driver(Xb, Yb, [&](v4f (&acc)[4][4], int jt) {
        (void)jt;
        #pragma unroll
        for (int mt = 0; mt < 4; ++mt)
            #pragma unroll
            for (int r = 0; r < 4; ++r) {
                float mm = acc[mt][0][r];
                #pragma unroll
                for (int nt = 1; nt < 4; ++nt) mm = fmaxf(mm, acc[mt][nt][r]);
                rmax[mt * 4 + r] = fmaxf(rmax[mt * 4 + r], mm);
            }
    });
    rmax_epilogue(rmax, gmaxp, i0, wr, wc, lr, lg);
}

__global__ void k_invd(const float* __restrict__ gmaxp, float* __restrict__ invd) {
    int i = blockIdx.x * 256 + threadIdx.x;
    float m = -3.0e38f;
    #pragma unroll
    for (int s = 0; s < NSLOT; ++s) m = fmaxf(m, gmaxp[(size_t)i * NSLOT + s]);
    invd[i] = 1.0f / ((1.0f - m) + 1e-5f);
}

__global__ __launch_bounds__(256, 2) void k_pass2(const unsigned short* __restrict__ Xb,
                                                  const unsigned short* __restrict__ Yb,
                                                  const float* __restrict__ invd,
                                                  float* __restrict__ zp) {
    const int t = threadIdx.x;
    const int w = t >> 6, l = t & 63;
    const int wr = w >> 1, wc = w & 1;
    const int lr = l & 15, lg = l >> 4;
    const int i0 = blockIdx.x * TI;
    float zs[16], c1[16], c2[16];
    #pragma unroll
    for (int u = 0; u < 16; ++u) {
        int row = i0 + wr * 64 + (u >> 2) * 16 + lg * 4 + (u & 3);
        float inv = invd[row];
        c2[u] = 2.0f * inv;
        c1[u] = 2.0f - 2.0f * inv;
        zs[u] = 0.f;
    }
    gemm_driver(Xb, Yb, [&](v4f (&acc)[4][4], int jt) {
        (void)jt;
        #pragma unroll
        for (int mt = 0; mt < 4; ++mt)
            #pragma unroll
            for (int r = 0; r < 4; ++r) {
                int u = mt * 4 + r;
                float s = 0.f;
                #pragma unroll
                for (int nt = 0; nt < 4; ++nt)
                    s += __expf(fmaf(c2[u], acc[mt][nt][r], c1[u]));
                zs[u] += s;
            }
    });
    #pragma unroll
    for (int u = 0; u < 16; ++u) {
        float z = zs[u];
        z += __shfl_xor(z, 1);
        z += __shfl_xor(z, 2);
        z += __shfl_xor(z, 4);
        z += __shfl_xor(z, 8);
        if (lr == 0) {
            int row = i0 + wr * 64 + (u >> 2) * 16 + lg * 4 + (u & 3);
            zp[(size_t)row * NSLOT + blockIdx.y * 2 + wc] = z;
        }
    }
}

__global__ void k_kmax(const float* __restrict__ zp, const float* __restrict__ gmaxp,
                       const unsigned short* __restrict__ Xb, const unsigned short* __restrict__ Yb,
                       float* __restrict__ accum, int* __restrict__ counter,
                       float* __restrict__ out) {
    int i = blockIdx.x * 256 + threadIdx.x;
    float Z = 0.f, gmax = -3.0e38f;
    #pragma unroll
    for (int s = 0; s < NSLOT; ++s) {
        Z += zp[(size_t)i * NSLOT + s];
        gmax = fmaxf(gmax, gmaxp[(size_t)i * NSLOT + s]);
    }
    float gii = 0.f;
    const uint2* xr = (const uint2*)(Xb + (size_t)i * NC);
    const uint2* yr = (const uint2*)(Yb + (size_t)i * NC);
    for (int c4 = 0; c4 < NC / 4; ++c4) {
        uint2 xa = xr[c4], ya = yr[c4];
        float x0 = __uint_as_float((xa.x & 0xFFFFu) << 16), y0 = __uint_as_float((ya.x & 0xFFFFu) << 16);
        float x1 = __uint_as_float(xa.x & 0xFFFF0000u),     y1 = __uint_as_float(ya.x & 0xFFFF0000u);
        float x2 = __uint_as_float((xa.y & 0xFFFFu) << 16), y2 = __uint_as_float((ya.y & 0xFFFFu) << 16);
        float x3 = __uint_as_float(xa.y & 0xFFFF0000u),     y3 = __uint_as_float(ya.y & 0xFFFF0000u);
        gii = fmaf(x0, y0, gii); gii = fmaf(x1, y1, gii);
        gii = fmaf(x2, y2, gii); gii = fmaf(x3, y3, gii);
    }
    float dmin = 1.0f - gmax;
    float inv = 1.0f / (dmin + 1e-5f);
    float wmx = __expf(2.0f - 2.0f * dmin * inv);
    float wii = __expf(2.0f - 2.0f * (1.0f - gii) * inv);
    float invZ = 1.0f / Z;
    float kmax = fmaxf(0.9f * wmx * invZ, 0.9f * wii * invZ + 0.1f);

    __shared__ float red[256];
    red[threadIdx.x] = kmax;
    __syncthreads();
    for (int off = 128; off > 0; off >>= 1) {
        if (threadIdx.x < off) red[threadIdx.x] += red[threadIdx.x + off];
        __syncthreads();
    }
    if (threadIdx.x == 0) {
        atomicAdd(accum, red[0]);
        __threadfence();
        int n = atomicAdd(counter, 1);
        if (n == (int)gridDim.x - 1) {
            float total = atomicAdd(accum, 0.0f);
            out[0] = -logf(total * (1.0f / HW) + 1e-5f);
        }
    }
}

extern "C" void kernel_launch(void* const* d_in, const int* in_sizes, int n_in,
                              void* d_out, int out_size, void* d_ws, size_t ws_size,
                              hipStream_t stream) {
    const float* x = (const float*)d_in[0];
    const float* y = (const float*)d_in[1];
    float* out = (float*)d_out;
    float* ws = (float*)d_ws;

    float* mu    = ws + MU_OFF;
    float* invd  = ws + INVD_OFF;
    float* gmaxp = ws + GMAXP_OFF;
    float* psx   = ws + GMAXP_OFF;            // aliases gmaxp (dead before pass1)
    float* psy   = ws + GMAXP_OFF + 8 * HW;
    float* zp    = ws + ZP_OFF;
    float* wdp   = ws + WDP_OFF;
    float* accum = ws + ACC_OFF;
    int*   counter = (int*)(accum + 1);
    unsigned short* Xb = (unsigned short*)((char*)d_ws + XB_BYTE);
    unsigned short* Yb = (unsigned short*)((char*)d_ws + YB_BYTE);
    unsigned int*   G2 = (unsigned int*)((char*)d_ws + G_BYTE);

    const bool bigws = ws_size >= (G_BYTE + G_BYTES);

    hipMemsetAsync(accum, 0, 8, stream);

    hipLaunchKernelGGL(k_mu, dim3(NC), dim3(256), 0, stream, y, mu);
    hipLaunchKernelGGL(k_sumsq, dim3(HW / 256, NC / 64), dim3(256), 0, stream, x, y, mu, psx, psy);
    hipLaunchKernelGGL(k_transpose, dim3(HW / 64, NC / 64, 2), dim3(256), 0, stream,
                       x, y, mu, psx, psy, Xb, Yb);

    dim3 grid(HW / TI, NCH);
    if (bigws) {
        hipLaunchKernelGGL(k_pass1s, grid, dim3(256), 0, stream, Xb, Yb, gmaxp, G2);
        hipLaunchKernelGGL(k_pass2s, dim3(NT16 / 4, NCYS), dim3(256), 0, stream, G2, gmaxp, zp, wdp);
        hipLaunchKernelGGL(k_kmax_s, dim3(HW / 256), dim3(256), 0, stream, zp, wdp, gmaxp,
                           accum, counter, out);
    } else {
        hipLaunchKernelGGL(k_pass1, grid, dim3(256), 0, stream, Xb, Yb, gmaxp);
        hipLaunchKernelGGL(k_invd, dim3(HW / 256), dim3(256), 0, stream, gmaxp, invd);
        hipLaunchKernelGGL(k_pass2, grid, dim3(256), 0, stream, Xb, Yb, invd, zp);
        hipLaunchKernelGGL(k_kmax, dim3(HW / 256), dim3(256), 0, stream, zp, gmaxp, Xb, Yb,
                           accum, counter, out);
    }
}

// Round 8
// 164.134 us; speedup vs baseline: 3.3815x; 1.0126x over previous
//
#include <hip/hip_runtime.h>
#include <hip/hip_bf16.h>
#include <math.h>

#define HW 6400
#define NC 512
#define NH 80
#define NW 80
#define NCH 25      // column chunks (blocks in y) for GEMM passes
#define NSLOT 50    // per-row gmax partial slots = NCH * 2
#define NCYS 8      // column chunks for streaming pass2
#define JCH 256     // columns per GEMM block
#define TI 128      // row tile per GEMM block
#define BK 64       // K tile
#define NT16 400    // 16x16 tiles per dimension (6400/16)

typedef __attribute__((ext_vector_type(8))) short short8;
typedef __attribute__((ext_vector_type(4))) float v4f;

// ---- workspace layout (float offsets) ----
#define MU_OFF    0
#define SQX_OFF   512                       // per-pixel sumsq partials -> sxi after normfin
#define SQY_OFF   (512 + HW)
#define ACC_OFF   (512 + 2*HW)              // accum, counter (zeroed with SQ region)
#define GMAXP_OFF (ACC_OFF + 64)            // HW*NSLOT
#define INVD_OFF  (GMAXP_OFF + HW*NSLOT)
#define ZP_OFF    (INVD_OFF + HW)           // HW*NSLOT (fallback) / HW*NCYS (stream)
#define WDP_OFF   (ZP_OFF + HW*NSLOT)       // HW*NCYS
#define F32_FLOATS (WDP_OFF + HW*NCYS)
#define XB_BYTE   ((size_t)(((F32_FLOATS*4) + 255) & ~255))
#define YB_BYTE   (XB_BYTE + (size_t)HW*NC*2)
#define G_BYTE    (YB_BYTE + (size_t)HW*NC*2)
#define G_BYTES   ((size_t)NT16 * NT16 * 256 * 2)   // 81,920,000

// async global->LDS, 16 B per lane, LDS dest = wave-uniform base + lane*16
typedef __attribute__((address_space(1))) unsigned int uint_g;
typedef __attribute__((address_space(3))) unsigned int uint_l;
__device__ __forceinline__ void gload16(const void* g, void* l) {
    __builtin_amdgcn_global_load_lds((const uint_g*)g, (uint_l*)l, 16, 0, 0);
}

__global__ void k_mu(const float* __restrict__ y, float* __restrict__ mu) {
    int c = blockIdx.x;
    const float* yc = y + (size_t)c * HW;
    float s = 0.f;
    for (int i = threadIdx.x; i < HW; i += 256) s += yc[i];
    __shared__ float red[256];
    red[threadIdx.x] = s;
    __syncthreads();
    for (int off = 128; off > 0; off >>= 1) {
        if (threadIdx.x < off) red[threadIdx.x] += red[threadIdx.x + off];
        __syncthreads();
    }
    if (threadIdx.x == 0) mu[c] = red[0] * (1.0f / HW);
}

// centered bf16 transpose (NO normalization — deferred to pass1s epilogue)
// + per-pixel sumsq partials via atomicAdd (sq zeroed by host memset).
__global__ void k_transpose(const float* __restrict__ x, const float* __restrict__ y,
                            const float* __restrict__ mu,
                            float* __restrict__ sqx, float* __restrict__ sqy,
                            unsigned short* __restrict__ xb, unsigned short* __restrict__ yb) {
    __shared__ float tile[64 * 68];
    const int t = threadIdx.x;
    const int i0 = blockIdx.x * 64;
    const int c0 = blockIdx.y * 64;
    const int z = blockIdx.z;
    const float* src = z ? y : x;
    float* sq = z ? sqy : sqx;
    unsigned short* dst = z ? yb : xb;

    #pragma unroll 4
    for (int it = 0; it < 16; ++it) {
        int cl = it * 4 + (t >> 6);
        int il = t & 63;
        float v = src[(size_t)(c0 + cl) * HW + i0 + il] - mu[c0 + cl];
        tile[il * 68 + cl] = v;
    }
    __syncthreads();
    // partial sum-of-squares: thread (il, q) sums 16 channels of pixel il
    {
        int il = t & 63, q = t >> 6;
        float s = 0.f;
        #pragma unroll
        for (int cl = q * 16; cl < q * 16 + 16; ++cl) {
            float v = tile[il * 68 + cl];
            s = fmaf(v, v, s);
        }
        atomicAdd(&sq[i0 + il], s);
    }
    #pragma unroll
    for (int it = 0; it < 2; ++it) {
        int il = t >> 2;
        int seg = (t & 3) + it * 4;
        unsigned int pk[4];
        #pragma unroll
        for (int p = 0; p < 4; ++p) {
            float v0 = tile[il * 68 + seg * 8 + p * 2];
            float v1 = tile[il * 68 + seg * 8 + p * 2 + 1];
            __hip_bfloat16 h0 = __float2bfloat16(v0);
            __hip_bfloat16 h1 = __float2bfloat16(v1);
            unsigned short u0 = *reinterpret_cast<unsigned short*>(&h0);
            unsigned short u1 = *reinterpret_cast<unsigned short*>(&h1);
            pk[p] = (unsigned int)u0 | ((unsigned int)u1 << 16);
        }
        uint4 val = make_uint4(pk[0], pk[1], pk[2], pk[3]);
        *(uint4*)&dst[(size_t)(i0 + il) * NC + c0 + seg * 8] = val;
    }
}

// in-place: sq -> 1/max(sqrt(sq), 1e-12)
__global__ void k_normfin(float* __restrict__ sqx, float* __restrict__ sqy) {
    int i = blockIdx.x * 256 + threadIdx.x;
    sqx[i] = 1.0f / fmaxf(sqrtf(sqx[i]), 1e-12f);
    sqy[i] = 1.0f / fmaxf(sqrtf(sqy[i]), 1e-12f);
}

__device__ __forceinline__ void rmax_epilogue(float (&rmax)[16], float* gmaxp,
                                              int i0, int wr, int wc, int lr, int lg) {
    #pragma unroll
    for (int u = 0; u < 16; ++u) {
        float v = rmax[u];
        v = fmaxf(v, __shfl_xor(v, 1));
        v = fmaxf(v, __shfl_xor(v, 2));
        v = fmaxf(v, __shfl_xor(v, 4));
        v = fmaxf(v, __shfl_xor(v, 8));
        if (lr == 0) {
            int row = i0 + wr * 64 + (u >> 2) * 16 + lg * 4 + (u & 3);
            gmaxp[(size_t)row * NSLOT + blockIdx.y * 2 + wc] = v;
        }
    }
}

// pass1 (stream): single-stage K loop — A tile (128x64) + BOTH B halves
// (256x64) staged per kt (48 KB LDS), wave tile 64x128 (acc[4][8]).
// Half the barriers of the jt-split version; A staged once, not twice.
// Normalization applied in the fp32 epilogue: G = raw_dot * sxi[i] * syi[j].
__global__ __launch_bounds__(256, 2) void k_pass1s(const unsigned short* __restrict__ Xb,
                                                   const unsigned short* __restrict__ Yb,
                                                   const float* __restrict__ sxi,
                                                   const float* __restrict__ syi,
                                                   float* __restrict__ gmaxp,
                                                   unsigned int* __restrict__ G2) {
    __shared__ char sA[128 * 128];   // 16 KB: [row][k] bf16, seg^(row&7) swizzle
    __shared__ char sB[256 * 128];   // 32 KB
    const int t = threadIdx.x;
    const int w = t >> 6, l = t & 63;
    const int wr = w >> 1, wc = w & 1;
    const int lr = l & 15, lg = l >> 4;
    const int i0 = blockIdx.x * TI;
    const int jbase = blockIdx.y * JCH;

    int aoff[4][2], boff[8][2];
    #pragma unroll
    for (int mt = 0; mt < 4; ++mt) {
        int row = wr * 64 + mt * 16 + lr;
        #pragma unroll
        for (int ks = 0; ks < 2; ++ks) {
            int seg = ks * 4 + lg;
            aoff[mt][ks] = row * 128 + ((seg ^ (row & 7)) * 16);
        }
    }
    #pragma unroll
    for (int nt = 0; nt < 8; ++nt) {
        int row = wc * 128 + nt * 16 + lr;
        #pragma unroll
        for (int ks = 0; ks < 2; ++ks) {
            int seg = ks * 4 + lg;
            boff[nt][ks] = row * 128 + ((seg ^ (row & 7)) * 16);
        }
    }

    // staging: wave w covers A rows [w*32, w*32+32) and B rows [w*64, w*64+64)
    const int strow = l >> 3;
    const int stcol = ((l & 7) ^ strow) * 8;
    const unsigned short* ga = Xb + (size_t)(i0 + w * 32 + strow) * NC + stcol;
    const unsigned short* gb = Yb + (size_t)(jbase + w * 64 + strow) * NC + stcol;
    char* dA = sA + w * 4096;
    char* dB = sB + w * 8192;

    v4f acc[4][8];
    #pragma unroll
    for (int mt = 0; mt < 4; ++mt)
        #pragma unroll
        for (int nt = 0; nt < 8; ++nt)
            acc[mt][nt] = (v4f){0.f, 0.f, 0.f, 0.f};

    #pragma unroll 1
    for (int kt = 0; kt < NC; kt += BK) {
        __syncthreads();
        gload16(ga + kt,           dA);
        gload16(ga + 8  * NC + kt, dA + 1024);
        gload16(ga + 16 * NC + kt, dA + 2048);
        gload16(ga + 24 * NC + kt, dA + 3072);
        #pragma unroll
        for (int it = 0; it < 8; ++it)
            gload16(gb + it * 8 * NC + kt, dB + it * 1024);
        __syncthreads();
        #pragma unroll
        for (int ks = 0; ks < 2; ++ks) {
            short8 af[4], bf[8];
            #pragma unroll
            for (int mt = 0; mt < 4; ++mt) af[mt] = *(const short8*)&sA[aoff[mt][ks]];
            #pragma unroll
            for (int nt = 0; nt < 8; ++nt) bf[nt] = *(const short8*)&sB[boff[nt][ks]];
            #pragma unroll
            for (int mt = 0; mt < 4; ++mt)
                #pragma unroll
                for (int nt = 0; nt < 8; ++nt)
                    acc[mt][nt] = __builtin_amdgcn_mfma_f32_16x16x32_bf16(
                        af[mt], bf[nt], acc[mt][nt], 0, 0, 0);
        }
    }

    // epilogue: scale to cosine, row-max, packed-bf16 tile store
    float rsx[16];
    #pragma unroll
    for (int u = 0; u < 16; ++u) {
        int row = i0 + wr * 64 + (u >> 2) * 16 + lg * 4 + (u & 3);
        rsx[u] = sxi[row];
    }
    float rsy[8];
    #pragma unroll
    for (int nt = 0; nt < 8; ++nt)
        rsy[nt] = syi[jbase + wc * 128 + nt * 16 + lr];

    float rmax[16];
    #pragma unroll
    for (int u = 0; u < 16; ++u) rmax[u] = -3.0e38f;

    #pragma unroll
    for (int mt = 0; mt < 4; ++mt) {
        size_t rbase = (size_t)(i0 / 16 + wr * 4 + mt) * (NT16 * 128);  // uint units
        #pragma unroll
        for (int nt = 0; nt < 8; ++nt) {
            int ct = jbase / 16 + wc * 8 + nt;
            float g0 = acc[mt][nt][0] * rsx[mt * 4 + 0] * rsy[nt];
            float g1 = acc[mt][nt][1] * rsx[mt * 4 + 1] * rsy[nt];
            float g2 = acc[mt][nt][2] * rsx[mt * 4 + 2] * rsy[nt];
            float g3 = acc[mt][nt][3] * rsx[mt * 4 + 3] * rsy[nt];
            rmax[mt * 4 + 0] = fmaxf(rmax[mt * 4 + 0], g0);
            rmax[mt * 4 + 1] = fmaxf(rmax[mt * 4 + 1], g1);
            rmax[mt * 4 + 2] = fmaxf(rmax[mt * 4 + 2], g2);
            rmax[mt * 4 + 3] = fmaxf(rmax[mt * 4 + 3], g3);
            __hip_bfloat16 h0 = __float2bfloat16(g0);
            __hip_bfloat16 h1 = __float2bfloat16(g1);
            __hip_bfloat16 h2 = __float2bfloat16(g2);
            __hip_bfloat16 h3 = __float2bfloat16(g3);
            unsigned int pk0 = (unsigned int)*(unsigned short*)&h0 | ((unsigned int)*(unsigned short*)&h1 << 16);
            unsigned int pk1 = (unsigned int)*(unsigned short*)&h2 | ((unsigned int)*(unsigned short*)&h3 << 16);
            *(uint2*)&G2[rbase + (size_t)ct * 128 + l * 2] = make_uint2(pk0, pk1);
        }
    }
    rmax_epilogue(rmax, gmaxp, i0, wr, wc, lr, lg);
}

// streaming pass2: read stored G tiles, inline dmin, exp-sum Z + diag weight.
__global__ __launch_bounds__(256) void k_pass2s(const unsigned int* __restrict__ G2,
                                                const float* __restrict__ gmaxp,
                                                float* __restrict__ zp,
                                                float* __restrict__ wdp) {
    const int t = threadIdx.x;
    const int w = t >> 6, l = t & 63;
    const int lr = l & 15, lg = l >> 4;
    const int rt = blockIdx.x * 4 + w;
    const int cy = blockIdx.y;

    float m = -3.0e38f;
    {
        int row = rt * 16 + lr;
        #pragma unroll
        for (int k = 0; k < 13; ++k) {
            int s = lg + 4 * k;
            if (s < NSLOT) m = fmaxf(m, gmaxp[(size_t)row * NSLOT + s]);
        }
        m = fmaxf(m, __shfl_xor(m, 16));
        m = fmaxf(m, __shfl_xor(m, 32));
    }
    float inv_lr = 1.0f / ((1.0f - m) + 1e-5f);
    float c1[4], c2[4];
    #pragma unroll
    for (int r = 0; r < 4; ++r) {
        float iv = __shfl(inv_lr, lg * 4 + r);
        c2[r] = 2.0f * iv;
        c1[r] = 2.0f - 2.0f * iv;
    }

    const uint2* base = (const uint2*)G2 + (size_t)rt * (NT16 * 64) + l;
    float zs[4] = {0.f, 0.f, 0.f, 0.f};
    #pragma unroll 4
    for (int ct = cy * 50; ct < cy * 50 + 50; ++ct) {
        uint2 v = base[(size_t)ct * 64];
        float g0 = __uint_as_float((v.x & 0xFFFFu) << 16);
        float g1 = __uint_as_float(v.x & 0xFFFF0000u);
        float g2 = __uint_as_float((v.y & 0xFFFFu) << 16);
        float g3 = __uint_as_float(v.y & 0xFFFF0000u);
        zs[0] += __expf(fmaf(c2[0], g0, c1[0]));
        zs[1] += __expf(fmaf(c2[1], g1, c1[1]));
        zs[2] += __expf(fmaf(c2[2], g2, c1[2]));
        zs[3] += __expf(fmaf(c2[3], g3, c1[3]));
    }
    float wd[4] = {0.f, 0.f, 0.f, 0.f};
    if (rt / 50 == cy) {
        uint2 v = base[(size_t)rt * 64];
        float g[4];
        g[0] = __uint_as_float((v.x & 0xFFFFu) << 16);
        g[1] = __uint_as_float(v.x & 0xFFFF0000u);
        g[2] = __uint_as_float((v.y & 0xFFFFu) << 16);
        g[3] = __uint_as_float(v.y & 0xFFFF0000u);
        #pragma unroll
        for (int r = 0; r < 4; ++r)
            if (lr == lg * 4 + r) wd[r] = __expf(fmaf(c2[r], g[r], c1[r]));
    }
    #pragma unroll
    for (int r = 0; r < 4; ++r) {
        float z = zs[r], d = wd[r];
        z += __shfl_xor(z, 1);  d += __shfl_xor(d, 1);
        z += __shfl_xor(z, 2);  d += __shfl_xor(d, 2);
        z += __shfl_xor(z, 4);  d += __shfl_xor(d, 4);
        z += __shfl_xor(z, 8);  d += __shfl_xor(d, 8);
        if (lr == 0) {
            int row = rt * 16 + lg * 4 + r;
            zp[(size_t)row * NCYS + cy] = z;
            wdp[(size_t)row * NCYS + cy] = d;
        }
    }
}

__global__ void k_kmax_s(const float* __restrict__ zp, const float* __restrict__ wdp,
                         const float* __restrict__ gmaxp, float* __restrict__ accum,
                         int* __restrict__ counter, float* __restrict__ out) {
    int i = blockIdx.x * 256 + threadIdx.x;
    float Z = 0.f, wd = 0.f, gmax = -3.0e38f;
    #pragma unroll
    for (int s = 0; s < NCYS; ++s) {
        Z += zp[(size_t)i * NCYS + s];
        wd += wdp[(size_t)i * NCYS + s];
    }
    #pragma unroll
    for (int s = 0; s < NSLOT; ++s) gmax = fmaxf(gmax, gmaxp[(size_t)i * NSLOT + s]);
    float dmin = 1.0f - gmax;
    float inv = 1.0f / (dmin + 1e-5f);
    float wmx = __expf(2.0f - 2.0f * dmin * inv);
    float invZ = 1.0f / Z;
    float kmax = fmaxf(0.9f * wmx * invZ, 0.9f * wd * invZ + 0.1f);

    __shared__ float red[256];
    red[threadIdx.x] = kmax;
    __syncthreads();
    for (int off = 128; off > 0; off >>= 1) {
        if (threadIdx.x < off) red[threadIdx.x] += red[threadIdx.x + off];
        __syncthreads();
    }
    if (threadIdx.x == 0) {
        atomicAdd(accum, red[0]);
        __threadfence();
        int n = atomicAdd(counter, 1);
        if (n == (int)gridDim.x - 1) {
            float total = atomicAdd(accum, 0.0f);
            out[0] = -logf(total * (1.0f / HW) + 1e-5f);
        }
    }
}

// ---------- fallback path (ws too small for G): two-GEMM, R7 driver ----------
template <typename F>
__device__ __forceinline__ void gemm_driver(const unsigned short* __restrict__ Xb,
                                            const unsigned short* __restrict__ Yb,
                                            F&& consume) {
    __shared__ char sA[TI * BK * 2];
    __shared__ char sB[TI * BK * 2];
    const int t = threadIdx.x;
    const int w = t >> 6, l = t & 63;
    const int wr = w >> 1, wc = w & 1;
    const int lr = l & 15, lg = l >> 4;
    const int i0 = blockIdx.x * TI;
    const int jbase = blockIdx.y * JCH;

    int aoff[4][2], boff[4][2];
    #pragma unroll
    for (int mt = 0; mt < 4; ++mt) {
        int row = wr * 64 + mt * 16 + lr;
        #pragma unroll
        for (int ks = 0; ks < 2; ++ks) {
            int seg = ks * 4 + lg;
            aoff[mt][ks] = row * 128 + ((seg ^ (row & 7)) * 16);
        }
    }
    #pragma unroll
    for (int nt = 0; nt < 4; ++nt) {
        int row = wc * 64 + nt * 16 + lr;
        #pragma unroll
        for (int ks = 0; ks < 2; ++ks) {
            int seg = ks * 4 + lg;
            boff[nt][ks] = row * 128 + ((seg ^ (row & 7)) * 16);
        }
    }
    const int strow = l >> 3;
    const int stcol = ((l & 7) ^ strow) * 8;
    char* dA0 = sA + (w * 4 + 0) * 1024;
    char* dA1 = sA + (w * 4 + 1) * 1024;
    char* dA2 = sA + (w * 4 + 2) * 1024;
    char* dA3 = sA + (w * 4 + 3) * 1024;
    char* dB0 = sB + (w * 4 + 0) * 1024;
    char* dB1 = sB + (w * 4 + 1) * 1024;
    char* dB2 = sB + (w * 4 + 2) * 1024;
    char* dB3 = sB + (w * 4 + 3) * 1024;
    const unsigned short* ga = Xb + (size_t)(i0 + w * 32 + strow) * NC + stcol;
    const unsigned short* gb0 = Yb + (size_t)(jbase + w * 32 + strow) * NC + stcol;

    #pragma unroll 1
    for (int jt = 0; jt < JCH; jt += TI) {
        const unsigned short* gb = gb0 + (size_t)jt * NC;
        v4f acc[4][4];
        #pragma unroll
        for (int mt = 0; mt < 4; ++mt)
            #pragma unroll
            for (int nt = 0; nt < 4; ++nt)
                acc[mt][nt] = (v4f){0.f, 0.f, 0.f, 0.f};

        #pragma unroll 1
        for (int kt = 0; kt < NC; kt += BK) {
            __syncthreads();
            gload16(ga + kt,           dA0);
            gload16(ga + 8  * NC + kt, dA1);
            gload16(ga + 16 * NC + kt, dA2);
            gload16(ga + 24 * NC + kt, dA3);
            gload16(gb + kt,           dB0);
            gload16(gb + 8  * NC + kt, dB1);
            gload16(gb + 16 * NC + kt, dB2);
            gload16(gb + 24 * NC + kt, dB3);
            __syncthreads();
            #pragma unroll
            for (int ks = 0; ks < 2; ++ks) {
                short8 af[4], bf[4];
                #pragma unroll
                for (int mt = 0; mt < 4; ++mt) af[mt] = *(const short8*)&sA[aoff[mt][ks]];
                #pragma unroll
                for (int nt = 0; nt < 4; ++nt) bf[nt] = *(const short8*)&sB[boff[nt][ks]];
                #pragma unroll
                for (int mt = 0; mt < 4; ++mt)
                    #pragma unroll
                    for (int nt = 0; nt < 4; ++nt)
                        acc[mt][nt] = __builtin_amdgcn_mfma_f32_16x16x32_bf16(
                            af[mt], bf[nt], acc[mt][nt], 0, 0, 0);
            }
        }
        consume(acc, jt);
    }
}

__global__ __launch_bounds__(256, 2) void k_pass1(const unsigned short* __restrict__ Xb,
                                                  const unsigned short* __restrict__ Yb,
                                                  const float* __restrict__ sxi,
                                                  const float* __restrict__ syi,
                                                  float* __restrict__ gmaxp) {
    const int t = threadIdx.x;
    const int w = t >> 6, l = t & 63;
    const int wr = w >> 1, wc = w & 1;
    const int lr = l & 15, lg = l >> 4;
    const int i0 = blockIdx.x * TI;
    const int jbase = blockIdx.y * JCH;
    float rsx[16], rmax[16];
    #pragma unroll
    for (int u = 0; u < 16; ++u) {
        int row = i0 + wr * 64 + (u >> 2) * 16 + lg * 4 + (u & 3);
        rsx[u] = sxi[row];
        rmax[u] = -3.0e38f;
    }
    gemm_driver(Xb, Yb, [&](v4f (&acc)[4][4], int jt) {
        #pragma unroll
        for (int nt = 0; nt < 4; ++nt) {
            float sy = syi[jbase + jt + (wc * 4 + nt) * 16 + lr];
            #pragma unroll
            for (int mt = 0; mt < 4; ++mt)
                #pragma unroll
                for (int r = 0; r < 4; ++r)
                    rmax[mt * 4 + r] = fmaxf(rmax[mt * 4 + r],
                                             acc[mt][nt][r] * rsx[mt * 4 + r] * sy);
        }
    });
    rmax_epilogue(rmax, gmaxp, i0, wr, wc, lr, lg);
}

__global__ void k_invd(const float* __restrict__ gmaxp, float* __restrict__ invd) {
    int i = blockIdx.x * 256 + threadIdx.x;
    float m = -3.0e38f;
    #pragma unroll
    for (int s = 0; s < NSLOT; ++s) m = fmaxf(m, gmaxp[(size_t)i * NSLOT + s]);
    invd[i] = 1.0f / ((1.0f - m) + 1e-5f);
}

__global__ __launch_bounds__(256, 2) void k_pass2(const unsigned short* __restrict__ Xb,
                                                  const unsigned short* __restrict__ Yb,
                                                  const float* __restrict__ sxi,
                                                  const float* __restrict__ syi,
                                                  const float* __restrict__ invd,
                                                  float* __restrict__ zp) {
    const int t = threadIdx.x;
    const int w = t >> 6, l = t & 63;
    const int wr = w >> 1, wc = w & 1;
    const int lr = l & 15, lg = l >> 4;
    const int i0 = blockIdx.x * TI;
    const int jbase = blockIdx.y * JCH;
    float zs[16], c1[16], c2[16], rsx[16];
    #pragma unroll
    for (int u = 0; u < 16; ++u) {
        int row = i0 + wr * 64 + (u >> 2) * 16 + lg * 4 + (u & 3);
        float inv = invd[row];
        c2[u] = 2.0f * inv;
        c1[u] = 2.0f - 2.0f * inv;
        rsx[u] = sxi[row];
        zs[u] = 0.f;
    }
    gemm_driver(Xb, Yb, [&](v4f (&acc)[4][4], int jt) {
        #pragma unroll
        for (int nt = 0; nt < 4; ++nt) {
            float sy = syi[jbase + jt + (wc * 4 + nt) * 16 + lr];
            #pragma unroll
            for (int mt = 0; mt < 4; ++mt)
                #pragma unroll
                for (int r = 0; r < 4; ++r) {
                    int u = mt * 4 + r;
                    float g = acc[mt][nt][r] * rsx[u] * sy;
                    zs[u] += __expf(fmaf(c2[u], g, c1[u]));
                }
        }
    });
    #pragma unroll
    for (int u = 0; u < 16; ++u) {
        float z = zs[u];
        z += __shfl_xor(z, 1);
        z += __shfl_xor(z, 2);
        z += __shfl_xor(z, 4);
        z += __shfl_xor(z, 8);
        if (lr == 0) {
            int row = i0 + wr * 64 + (u >> 2) * 16 + lg * 4 + (u & 3);
            zp[(size_t)row * NSLOT + blockIdx.y * 2 + wc] = z;
        }
    }
}

__global__ void k_kmax(const float* __restrict__ zp, const float* __restrict__ gmaxp,
                       const unsigned short* __restrict__ Xb, const unsigned short* __restrict__ Yb,
                       const float* __restrict__ sxi, const float* __restrict__ syi,
                       float* __restrict__ accum, int* __restrict__ counter,
                       float* __restrict__ out) {
    int i = blockIdx.x * 256 + threadIdx.x;
    float Z = 0.f, gmax = -3.0e38f;
    #pragma unroll
    for (int s = 0; s < NSLOT; ++s) {
        Z += zp[(size_t)i * NSLOT + s];
        gmax = fmaxf(gmax, gmaxp[(size_t)i * NSLOT + s]);
    }
    float gii = 0.f;
    const uint2* xr = (const uint2*)(Xb + (size_t)i * NC);
    const uint2* yr = (const uint2*)(Yb + (size_t)i * NC);
    for (int c4 = 0; c4 < NC / 4; ++c4) {
        uint2 xa = xr[c4], ya = yr[c4];
        float x0 = __uint_as_float((xa.x & 0xFFFFu) << 16), y0 = __uint_as_float((ya.x & 0xFFFFu) << 16);
        float x1 = __uint_as_float(xa.x & 0xFFFF0000u),     y1 = __uint_as_float(ya.x & 0xFFFF0000u);
        float x2 = __uint_as_float((xa.y & 0xFFFFu) << 16), y2 = __uint_as_float((ya.y & 0xFFFFu) << 16);
        float x3 = __uint_as_float(xa.y & 0xFFFF0000u),     y3 = __uint_as_float(ya.y & 0xFFFF0000u);
        gii = fmaf(x0, y0, gii); gii = fmaf(x1, y1, gii);
        gii = fmaf(x2, y2, gii); gii = fmaf(x3, y3, gii);
    }
    gii *= sxi[i] * syi[i];
    float dmin = 1.0f - gmax;
    float inv = 1.0f / (dmin + 1e-5f);
    float wmx = __expf(2.0f - 2.0f * dmin * inv);
    float wii = __expf(2.0f - 2.0f * (1.0f - gii) * inv);
    float invZ = 1.0f / Z;
    float kmax = fmaxf(0.9f * wmx * invZ, 0.9f * wii * invZ + 0.1f);

    __shared__ float red[256];
    red[threadIdx.x] = kmax;
    __syncthreads();
    for (int off = 128; off > 0; off >>= 1) {
        if (threadIdx.x < off) red[threadIdx.x] += red[threadIdx.x + off];
        __syncthreads();
    }
    if (threadIdx.x == 0) {
        atomicAdd(accum, red[0]);
        __threadfence();
        int n = atomicAdd(counter, 1);
        if (n == (int)gridDim.x - 1) {
            float total = atomicAdd(accum, 0.0f);
            out[0] = -logf(total * (1.0f / HW) + 1e-5f);
        }
    }
}

extern "C" void kernel_launch(void* const* d_in, const int* in_sizes, int n_in,
                              void* d_out, int out_size, void* d_ws, size_t ws_size,
                              hipStream_t stream) {
    const float* x = (const float*)d_in[0];
    const float* y = (const float*)d_in[1];
    float* out = (float*)d_out;
    float* ws = (float*)d_ws;

    float* mu    = ws + MU_OFF;
    float* sqx   = ws + SQX_OFF;   // -> sxi after k_normfin
    float* sqy   = ws + SQY_OFF;   // -> syi after k_normfin
    float* accum = ws + ACC_OFF;
    int*   counter = (int*)(accum + 1);
    float* gmaxp = ws + GMAXP_OFF;
    float* invd  = ws + INVD_OFF;
    float* zp    = ws + ZP_OFF;
    float* wdp   = ws + WDP_OFF;
    unsigned short* Xb = (unsigned short*)((char*)d_ws + XB_BYTE);
    unsigned short* Yb = (unsigned short*)((char*)d_ws + YB_BYTE);
    unsigned int*   G2 = (unsigned int*)((char*)d_ws + G_BYTE);

    const bool bigws = ws_size >= (G_BYTE + G_BYTES);

    // zero sumsq accumulators + accum/counter in one shot
    hipMemsetAsync(sqx, 0, (2 * HW + 64) * sizeof(float), stream);

    hipLaunchKernelGGL(k_mu, dim3(NC), dim3(256), 0, stream, y, mu);
    hipLaunchKernelGGL(k_transpose, dim3(HW / 64, NC / 64, 2), dim3(256), 0, stream,
                       x, y, mu, sqx, sqy, Xb, Yb);
    hipLaunchKernelGGL(k_normfin, dim3(HW / 256), dim3(256), 0, stream, sqx, sqy);

    dim3 grid(HW / TI, NCH);
    if (bigws) {
        hipLaunchKernelGGL(k_pass1s, grid, dim3(256), 0, stream, Xb, Yb, sqx, sqy, gmaxp, G2);
        hipLaunchKernelGGL(k_pass2s, dim3(NT16 / 4, NCYS), dim3(256), 0, stream, G2, gmaxp, zp, wdp);
        hipLaunchKernelGGL(k_kmax_s, dim3(HW / 256), dim3(256), 0, stream, zp, wdp, gmaxp,
                           accum, counter, out);
    } else {
        hipLaunchKernelGGL(k_pass1, grid, dim3(256), 0, stream, Xb, Yb, sqx, sqy, gmaxp);
        hipLaunchKernelGGL(k_invd, dim3(HW / 256), dim3(256), 0, stream, gmaxp, invd);
        hipLaunchKernelGGL(k_pass2, grid, dim3(256), 0, stream, Xb, Yb, sqx, sqy, invd, zp);
        hipLaunchKernelGGL(k_kmax, dim3(HW / 256), dim3(256), 0, stream, zp, gmaxp, Xb, Yb,
                           sqx, sqy, accum, counter, out);
    }
}